// Round 7
// baseline (1230.457 us; speedup 1.0000x reference)
//
#include <hip/hip_runtime.h>

#define NN 50000
#define EE 800000
#define ETOT 850000
#define KIN 61
#define HH 256
#define NH 8
#define CC 32
#define LL 4
#define SCAN_NBLK 49   // ceil(NN/1024)

typedef __attribute__((ext_vector_type(8))) short bf16x8;
typedef __attribute__((ext_vector_type(4))) float f32x4;

__device__ __forceinline__ unsigned short f2b(float f) {
    unsigned u = __builtin_bit_cast(unsigned, f);
    u += 0x7fffu + ((u >> 16) & 1u);   // RNE
    return (unsigned short)(u >> 16);
}
__device__ __forceinline__ float b2f(unsigned short h) {
    unsigned u = ((unsigned)h) << 16;
    return __builtin_bit_cast(float, u);
}

// async global->LDS, 16B per lane; LDS dest is wave-uniform base + lane*16
__device__ __forceinline__ void gload16(const void* g, void* l) {
    __builtin_amdgcn_global_load_lds(
        (const __attribute__((address_space(1))) void*)g,
        (__attribute__((address_space(3))) void*)l, 16, 0, 0);
}

// ============================ CSR build ============================

__global__ __launch_bounds__(256) void edge_hist(const int* __restrict__ ei,
                                                 int* __restrict__ counts) {
    int e = blockIdx.x * 256 + threadIdx.x;
    if (e >= ETOT) return;
    int d = (e < EE) ? ei[EE + e] : (e - EE);
    atomicAdd(&counts[d], 1);
}

__global__ __launch_bounds__(256) void scan1(const int* __restrict__ counts,
                                             int* __restrict__ tmp,
                                             int* __restrict__ bsums) {
    __shared__ int lds[256];
    int b = blockIdx.x, t = threadIdx.x;
    int base = b * 1024 + t * 4;
    int v0 = 0, v1 = 0, v2 = 0, v3 = 0;
    if (base + 0 < NN) v0 = counts[base + 0];
    if (base + 1 < NN) v1 = counts[base + 1];
    if (base + 2 < NN) v2 = counts[base + 2];
    if (base + 3 < NN) v3 = counts[base + 3];
    int s = v0 + v1 + v2 + v3;
    lds[t] = s;
    __syncthreads();
    for (int off = 1; off < 256; off <<= 1) {
        int x = (t >= off) ? lds[t - off] : 0;
        __syncthreads();
        lds[t] += x;
        __syncthreads();
    }
    int run = lds[t] - s;
    if (t == 255) bsums[b] = lds[255];
    run += v0; if (base + 0 < NN) tmp[base + 0] = run;
    run += v1; if (base + 1 < NN) tmp[base + 1] = run;
    run += v2; if (base + 2 < NN) tmp[base + 2] = run;
    run += v3; if (base + 3 < NN) tmp[base + 3] = run;
}

__global__ void scan2(int* __restrict__ bsums) {
    if (threadIdx.x == 0) {
        int acc = 0;
        for (int i = 0; i < SCAN_NBLK; ++i) { int t = bsums[i]; bsums[i] = acc; acc += t; }
    }
}

__global__ __launch_bounds__(256) void scan3(const int* __restrict__ tmp,
                                             const int* __restrict__ bsums,
                                             const int* __restrict__ counts,
                                             int* __restrict__ rowptr,
                                             int* __restrict__ cursor) {
    int i = blockIdx.x * 256 + threadIdx.x;
    if (i >= NN) return;
    int incl = tmp[i] + bsums[i >> 10];
    rowptr[i + 1] = incl;
    cursor[i] = incl - counts[i];
    if (i == 0) rowptr[0] = 0;
}

__global__ __launch_bounds__(256) void edge_scatter(const int* __restrict__ ei,
                                                    int* __restrict__ cursor,
                                                    int* __restrict__ ssrc) {
    int e = blockIdx.x * 256 + threadIdx.x;
    if (e >= ETOT) return;
    int s, d;
    if (e < EE) { s = ei[e]; d = ei[EE + e]; } else { s = d = e - EE; }
    int pos = atomicAdd(&cursor[d], 1);
    ssrc[pos] = s;
}

// sort each row's sources ascending (deterministic 64-lane bitonic).
__global__ __launch_bounds__(256) void sort_rows(const int* __restrict__ rowptr,
                                                 int* __restrict__ ssrc) {
    int wid = (blockIdx.x * 256 + threadIdx.x) >> 6;
    int lane = threadIdx.x & 63;
    if (wid >= NN) return;
    int beg = rowptr[wid], end = rowptr[wid + 1];
    int L = end - beg;
    if (L > 64) return;
    int v = (lane < L) ? ssrc[beg + lane] : 0x7fffffff;
#pragma unroll
    for (int k = 2; k <= 64; k <<= 1) {
#pragma unroll
        for (int j = k >> 1; j > 0; j >>= 1) {
            int partner = __shfl_xor(v, j);
            bool up = ((lane & k) == 0);
            bool keepMin = (up == ((lane & j) == 0));
            int mn = min(v, partner), mx = max(v, partner);
            v = keepMin ? mn : mx;
        }
    }
    if (lane < L) ssrc[beg + lane] = v;
}

// ============================ weight / input prep (bf16) ============================

__global__ __launch_bounds__(256) void prep_wt(const float* __restrict__ Ws,
                                               unsigned short* __restrict__ WT) {
    int t = blockIdx.x * 256 + threadIdx.x;
    if (t >= LL * HH * HH) return;
    int l = t >> 16, rem = t & 65535;
    int n = rem >> 8, k = rem & 255;
    WT[t] = f2b(Ws[l * 65536 + k * HH + n]);
}

__global__ __launch_bounds__(256) void prep_inwt(const float* __restrict__ in_W,
                                                 unsigned short* __restrict__ WT) {
    int t = blockIdx.x * 256 + threadIdx.x;
    if (t >= HH * 64) return;
    int n = t >> 6, k = t & 63;
    WT[t] = (k < KIN) ? f2b(in_W[k * HH + n]) : 0;
}

__global__ __launch_bounds__(256) void prep_x(const float* __restrict__ x,
                                              unsigned short* __restrict__ xb) {
    int t = blockIdx.x * 256 + threadIdx.x;
    if (t >= NN * 64) return;
    int n = t >> 6, c = t & 63;
    xb[t] = (c < KIN) ? f2b(x[n * KIN + c]) : 0;
}

// ============================ MFMA GEMM  C = A @ Bt^T ============================
// tile 128x128x64, 4 waves (2x2), each wave 64x64 via 4x4 16x16x32 frags.
// ZHM=0: C row-major [M][256]. ZHM=1: C head-major zT[c>>5][row][c&31]
// (per-head 3.2MB slices, L2-resident for the head-affine aggregate).
// Launch with gridDim.y = HH/128 = 2 ALWAYS.
template<int ZHM>
__global__ __launch_bounds__(256) void gemm_mfma(const unsigned short* __restrict__ A,
                                                 const unsigned short* __restrict__ Bt,
                                                 unsigned short* __restrict__ C,
                                                 int M, int K) {
    __shared__ unsigned short As[128 * 64];
    __shared__ unsigned short Bs[128 * 64];
    int row0 = blockIdx.x * 128;
    int n0 = blockIdx.y * 128;
    int tid = threadIdx.x;
    int w = tid >> 6, l = tid & 63;
    int wm = w >> 1, wn = w & 1;
    int r15 = l & 15, q = l >> 4;

    f32x4 acc[4][4] = {};

    int crow = l >> 3;     // row within 8-row chunk
    int cs   = l & 7;      // 16B slot within row

    for (int kt = 0; kt < K; kt += 64) {
        if (kt) __syncthreads();
#pragma unroll
        for (int c = 0; c < 4; ++c) {
            int r = w * 32 + c * 8 + crow;          // tile row 0..127
            int sg = cs ^ (r & 7);                  // pre-swizzled source slot
            int ga = row0 + r; if (ga >= M) ga = M - 1;
            gload16(&A[(size_t)ga * K + kt + sg * 8], &As[(w * 32 + c * 8) * 64]);
            int gb = n0 + r;                        // < 256 always
            gload16(&Bt[(size_t)gb * K + kt + sg * 8], &Bs[(w * 32 + c * 8) * 64]);
        }
        __syncthreads();
#pragma unroll
        for (int kk = 0; kk < 2; ++kk) {
            bf16x8 aF[4], bF[4];
#pragma unroll
            for (int i = 0; i < 4; ++i) {
                int ar = wm * 64 + i * 16 + r15;
                aF[i] = *(bf16x8*)&As[ar * 64 + ((kk * 4 + q) ^ (ar & 7)) * 8];
                int br = wn * 64 + i * 16 + r15;
                bF[i] = *(bf16x8*)&Bs[br * 64 + ((kk * 4 + q) ^ (br & 7)) * 8];
            }
#pragma unroll
            for (int i = 0; i < 4; ++i)
#pragma unroll
                for (int j = 0; j < 4; ++j)
                    acc[i][j] = __builtin_amdgcn_mfma_f32_16x16x32_bf16(aF[i], bF[j], acc[i][j], 0, 0, 0);
        }
    }

    // C/D layout: col = lane&15, row = (lane>>4)*4 + reg
#pragma unroll
    for (int i = 0; i < 4; ++i)
#pragma unroll
        for (int j = 0; j < 4; ++j) {
            int nc = n0 + wn * 64 + j * 16 + r15;
#pragma unroll
            for (int r = 0; r < 4; ++r) {
                int gr = row0 + wm * 64 + i * 16 + q * 4 + r;
                if (gr < M) {
                    if (ZHM)
                        C[(size_t)(nc >> 5) * NN * CC + (size_t)gr * CC + (nc & 31)] = f2b(acc[i][j][r]);
                    else
                        C[(size_t)gr * HH + nc] = f2b(acc[i][j][r]);
                }
            }
        }
}

// ============================ attention scores (zT head-major) ============================
// thread t: hd = t/NN, n = t%NN -> coalesced zT reads AND coalesced esrcT/edstT writes.
__global__ __launch_bounds__(256) void attn_scores(const unsigned short* __restrict__ zT,
                                                   const float* __restrict__ asrc,
                                                   const float* __restrict__ adst,
                                                   float* __restrict__ esrcT,
                                                   float* __restrict__ edstT) {
    int t = blockIdx.x * 256 + threadIdx.x;
    if (t >= NN * NH) return;
    int hd = t / NN, n = t - hd * NN;
    const unsigned short* zp = zT + (size_t)hd * NN * CC + (size_t)n * CC;
    const float* ap = asrc + hd * CC;
    const float* bp = adst + hd * CC;
    float s = 0.f, d = 0.f;
#pragma unroll
    for (int c = 0; c < CC; c += 4) {
        ushort4 zv = *(const ushort4*)(zp + c);
        float z0 = b2f(zv.x), z1 = b2f(zv.y), z2 = b2f(zv.z), z3 = b2f(zv.w);
        s += z0 * ap[c] + z1 * ap[c + 1] + z2 * ap[c + 2] + z3 * ap[c + 3];
        d += z0 * bp[c] + z1 * bp[c + 1] + z2 * bp[c + 2] + z3 * bp[c + 3];
    }
    esrcT[t] = s;   // t == hd*NN + n
    edstT[t] = d;
}

// ============================ head-affine aggregate ============================
// blockIdx.x & 7 == head -> round-robin dispatch pins head hd's z-slice (3.2MB)
// + esrcT slice (200KB) in ONE XCD's 4MB L2. Block = 4 waves = 4 nodes, 1 head.
// Wave: 4 edge-groups x 16 lanes (2 ch/lane, 64B/edge gather); fixed butterfly
// combine -> deterministic. No max-subtraction needed (|e| <~ 16).
__global__ __launch_bounds__(256) void aggregate(const int* __restrict__ rowptr,
                                                 const int* __restrict__ ssrc,
                                                 const float* __restrict__ esrcT,
                                                 const float* __restrict__ edstT,
                                                 const unsigned short* __restrict__ zT,
                                                 unsigned short* __restrict__ outb) {
    int bid = blockIdx.x;
    int hd = bid & 7;
    int chunk = bid >> 3;
    int w = threadIdx.x >> 6;
    int n = chunk * 4 + w;                 // NN % 4 == 0 -> always < NN
    int lane = threadIdx.x & 63;
    int g = lane >> 4;                     // edge group 0..3
    int col = lane & 15;                   // channels col*2, col*2+1
    const float* esp = esrcT + (size_t)hd * NN;
    const unsigned short* zp = zT + (size_t)hd * NN * CC;
    float ed = edstT[(size_t)hd * NN + n];
    int beg = rowptr[n], end = rowptr[n + 1];
    float a0 = 0.f, a1 = 0.f, den = 0.f;
    for (int i = beg + g; i < end; i += 4) {
        int s = ssrc[i];
        float es = esp[s];
        unsigned zz = *(const unsigned*)&zp[(size_t)s * CC + col * 2];
        float e = es + ed; e = (e > 0.f) ? e : 0.2f * e;
        float pc = __expf(e);
        den += pc;
        a0 += pc * b2f((unsigned short)(zz & 0xffffu));
        a1 += pc * b2f((unsigned short)(zz >> 16));
    }
    // combine the 4 groups (butterfly over lane bits 4,5 — fixed order)
    a0 += __shfl_xor(a0, 16); a1 += __shfl_xor(a1, 16); den += __shfl_xor(den, 16);
    a0 += __shfl_xor(a0, 32); a1 += __shfl_xor(a1, 32); den += __shfl_xor(den, 32);
    if (g == 0) {
        float inv = 1.f / den;             // row nonempty (self loop)
        unsigned short o0 = f2b(a0 * inv), o1 = f2b(a1 * inv);
        unsigned o = ((unsigned)o1 << 16) | (unsigned)o0;
        *(unsigned*)&outb[(size_t)n * HH + hd * CC + col * 2] = o;
    }
}

// ============================ BatchNorm ============================
__global__ __launch_bounds__(256) void col_stats(const unsigned short* __restrict__ X,
                                                 float* __restrict__ sums) {
    int c = threadIdx.x;
    int rows_per_block = (NN + gridDim.x - 1) / gridDim.x;
    int r0 = blockIdx.x * rows_per_block;
    int r1 = min(NN, r0 + rows_per_block);
    float s = 0.f, q = 0.f;
    for (int r = r0; r < r1; ++r) {
        float v = b2f(X[(size_t)r * HH + c]);
        s += v; q += v * v;
    }
    atomicAdd(&sums[c], s);
    atomicAdd(&sums[HH + c], q);
}

// out = relu((X-mean)*rstd*gamma+beta) [+ res]; all bf16; res/out may alias (same index).
__global__ __launch_bounds__(256) void bn_relu_add(const unsigned short* __restrict__ X,
                                                   const float* __restrict__ sums,
                                                   const float* __restrict__ gamma,
                                                   const float* __restrict__ beta,
                                                   const unsigned short* __restrict__ res,
                                                   unsigned short* __restrict__ outb) {
    int i = blockIdx.x * 256 + threadIdx.x;
    if (i >= NN * 64) return;
    int c4 = (i & 63) * 4;
    const float invN = 1.f / NN;
    ushort4 u = *(const ushort4*)(X + (size_t)i * 4);
    float v0 = b2f(u.x), v1 = b2f(u.y), v2 = b2f(u.z), v3 = b2f(u.w);
    float4 s1 = *(const float4*)&sums[c4];
    float4 s2 = *(const float4*)&sums[HH + c4];
    float4 gm = *(const float4*)&gamma[c4];
    float4 bt = *(const float4*)&beta[c4];
    float mn0 = s1.x * invN, mn1 = s1.y * invN, mn2 = s1.z * invN, mn3 = s1.w * invN;
    float rs0 = rsqrtf(fmaxf(s2.x * invN - mn0 * mn0, 0.f) + 1e-5f);
    float rs1 = rsqrtf(fmaxf(s2.y * invN - mn1 * mn1, 0.f) + 1e-5f);
    float rs2 = rsqrtf(fmaxf(s2.z * invN - mn2 * mn2, 0.f) + 1e-5f);
    float rs3 = rsqrtf(fmaxf(s2.w * invN - mn3 * mn3, 0.f) + 1e-5f);
    float r0 = fmaxf((v0 - mn0) * rs0 * gm.x + bt.x, 0.f);
    float r1 = fmaxf((v1 - mn1) * rs1 * gm.y + bt.y, 0.f);
    float r2 = fmaxf((v2 - mn2) * rs2 * gm.z + bt.z, 0.f);
    float r3 = fmaxf((v3 - mn3) * rs3 * gm.w + bt.w, 0.f);
    if (res) {
        ushort4 rv = *(const ushort4*)(res + (size_t)i * 4);
        r0 += b2f(rv.x); r1 += b2f(rv.y); r2 += b2f(rv.z); r3 += b2f(rv.w);
    }
    ushort4 ob;
    ob.x = f2b(r0); ob.y = f2b(r1); ob.z = f2b(r2); ob.w = f2b(r3);
    *(ushort4*)(outb + (size_t)i * 4) = ob;
}

// ============================ output projection (h bf16) ============================
__global__ __launch_bounds__(256) void out_proj(const unsigned short* __restrict__ h,
                                                const float* __restrict__ mW,
                                                const float* __restrict__ mb,
                                                const float* __restrict__ lW,
                                                const float* __restrict__ lb,
                                                float* __restrict__ out) {
    int wid = (blockIdx.x * 256 + threadIdx.x) >> 6;
    int lane = threadIdx.x & 63;
    if (wid >= NN) return;
    ushort4 hv = *(const ushort4*)&h[(size_t)wid * HH + lane * 4];
    float h0 = b2f(hv.x), h1 = b2f(hv.y), h2 = b2f(hv.z), h3 = b2f(hv.w);
    float4 wv = *(const float4*)&mW[lane * 4];
    float4 lv = *(const float4*)&lW[lane * 4];
    float sm = h0 * wv.x + h1 * wv.y + h2 * wv.z + h3 * wv.w;
    float sl = h0 * lv.x + h1 * lv.y + h2 * lv.z + h3 * lv.w;
    for (int off = 32; off > 0; off >>= 1) {
        sm += __shfl_down(sm, off);
        sl += __shfl_down(sl, off);
    }
    if (lane == 0) {
        out[wid] = sm + mb[0];
        float l = sl + lb[0];
        out[NN + wid] = fminf(10.f, fmaxf(-10.f, l));
    }
}

// ============================ launch ============================
extern "C" void kernel_launch(void* const* d_in, const int* in_sizes, int n_in,
                              void* d_out, int out_size, void* d_ws, size_t ws_size,
                              hipStream_t stream) {
    const float* x        = (const float*)d_in[0];
    const int*   ei       = (const int*)d_in[1];
    const float* in_W     = (const float*)d_in[2];
    const float* in_gamma = (const float*)d_in[4];
    const float* in_beta  = (const float*)d_in[5];
    const float* Ws       = (const float*)d_in[6];
    const float* att_src  = (const float*)d_in[7];
    const float* att_dst  = (const float*)d_in[8];
    const float* bn_gamma = (const float*)d_in[10];
    const float* bn_beta  = (const float*)d_in[11];
    const float* mean_W   = (const float*)d_in[12];
    const float* mean_b   = (const float*)d_in[13];
    const float* lv_W     = (const float*)d_in[14];
    const float* lv_b     = (const float*)d_in[15];
    float* out = (float*)d_out;

    // workspace layout (bytes)
    char* p = (char*)d_ws;
    unsigned short* z    = (unsigned short*)p; p += (size_t)NN * HH * 2;   // zT for layers
    unsigned short* hb   = (unsigned short*)p; p += (size_t)NN * HH * 2;
    unsigned short* aggb = (unsigned short*)p; p += (size_t)NN * HH * 2;
    float* esrcT = (float*)p;                  p += (size_t)NN * NH * 4;
    float* edstT = (float*)p;                  p += (size_t)NN * NH * 4;
    float* sums = (float*)p;                   p += 512 * 4;
    unsigned short* WT   = (unsigned short*)p; p += (size_t)LL * HH * HH * 2;
    unsigned short* inWT = (unsigned short*)p; p += (size_t)HH * 64 * 2;
    int* counts = (int*)p;                     p += (size_t)NN * 4;
    int* rowptr = (int*)p;                     p += (size_t)(NN + 1) * 4;
    int* cursor = (int*)p;                     p += (size_t)NN * 4;
    int* ssrc   = (int*)p;                     p += (size_t)ETOT * 4;
    int* bsums  = (int*)p;                     p += 64 * 4;
    unsigned short* xb = aggb;  // alias: xb dead before aggb first written

    // ---- CSR build (+ per-row source sort: locality + canonical order) ----
    hipMemsetAsync(counts, 0, NN * sizeof(int), stream);
    edge_hist<<<(ETOT + 255) / 256, 256, 0, stream>>>(ei, counts);
    scan1<<<SCAN_NBLK, 256, 0, stream>>>(counts, cursor, bsums);
    scan2<<<1, 64, 0, stream>>>(bsums);
    scan3<<<(NN + 255) / 256, 256, 0, stream>>>(cursor, bsums, counts, rowptr, cursor);
    edge_scatter<<<(ETOT + 255) / 256, 256, 0, stream>>>(ei, cursor, ssrc);
    sort_rows<<<(NN * 64 + 255) / 256, 256, 0, stream>>>(rowptr, ssrc);

    // ---- bf16 prep ----
    prep_wt<<<(LL * HH * HH + 255) / 256, 256, 0, stream>>>(Ws, WT);
    prep_inwt<<<(HH * 64 + 255) / 256, 256, 0, stream>>>(in_W, inWT);
    prep_x<<<(NN * 64 + 255) / 256, 256, 0, stream>>>(x, xb);

    // ---- input projection + BN + ReLU (row-major z: feeds only BN chain) ----
    {
        dim3 g((NN + 127) / 128, 2);
        gemm_mfma<0><<<g, 256, 0, stream>>>(xb, inWT, z, NN, 64);
    }
    hipMemsetAsync(sums, 0, 512 * sizeof(float), stream);
    col_stats<<<1024, 256, 0, stream>>>(z, sums);
    bn_relu_add<<<(NN * 64 + 255) / 256, 256, 0, stream>>>(z, sums, in_gamma, in_beta,
                                                           nullptr, hb);

    // ---- GAT layers ----
    for (int l = 0; l < LL; ++l) {
        const unsigned short* WTl = WT + (size_t)l * HH * HH;
        const float* asl = att_src + (size_t)l * NH * CC;
        const float* adl = att_dst + (size_t)l * NH * CC;
        const float* gl  = bn_gamma + (size_t)l * HH;
        const float* bl  = bn_beta + (size_t)l * HH;

        dim3 g((NN + 127) / 128, 2);
        gemm_mfma<1><<<g, 256, 0, stream>>>(hb, WTl, z, NN, HH);       // z head-major
        attn_scores<<<(NN * NH + 255) / 256, 256, 0, stream>>>(z, asl, adl, esrcT, edstT);
        aggregate<<<(NN / 4) * 8, 256, 0, stream>>>(rowptr, ssrc, esrcT, edstT, z, aggb);
        hipMemsetAsync(sums, 0, 512 * sizeof(float), stream);
        col_stats<<<1024, 256, 0, stream>>>(aggb, sums);
        bn_relu_add<<<(NN * 64 + 255) / 256, 256, 0, stream>>>(aggb, sums, gl, bl, hb, hb);
    }

    // ---- output heads ----
    out_proj<<<(NN * 64 + 255) / 256, 256, 0, stream>>>(hb, mean_W, mean_b, lv_W, lv_b, out);
}

// Round 8
// 1070.668 us; speedup vs baseline: 1.1492x; 1.1492x over previous
//
#include <hip/hip_runtime.h>

#define NN 50000
#define EE 800000
#define ETOT 850000
#define KIN 61
#define HH 256
#define NH 8
#define CC 32
#define LL 4
#define SCAN_NBLK 49   // ceil(NN/1024)

typedef __attribute__((ext_vector_type(8))) short bf16x8;
typedef __attribute__((ext_vector_type(4))) float f32x4;

__device__ __forceinline__ unsigned short f2b(float f) {
    unsigned u = __builtin_bit_cast(unsigned, f);
    u += 0x7fffu + ((u >> 16) & 1u);   // RNE
    return (unsigned short)(u >> 16);
}
__device__ __forceinline__ float b2f(unsigned short h) {
    unsigned u = ((unsigned)h) << 16;
    return __builtin_bit_cast(float, u);
}

// async global->LDS, 16B per lane; LDS dest is wave-uniform base + lane*16
__device__ __forceinline__ void gload16(const void* g, void* l) {
    __builtin_amdgcn_global_load_lds(
        (const __attribute__((address_space(1))) void*)g,
        (__attribute__((address_space(3))) void*)l, 16, 0, 0);
}

// ============================ CSR build ============================

__global__ __launch_bounds__(256) void edge_hist(const int* __restrict__ ei,
                                                 int* __restrict__ counts) {
    int e = blockIdx.x * 256 + threadIdx.x;
    if (e >= ETOT) return;
    int d = (e < EE) ? ei[EE + e] : (e - EE);
    atomicAdd(&counts[d], 1);
}

__global__ __launch_bounds__(256) void scan1(const int* __restrict__ counts,
                                             int* __restrict__ tmp,
                                             int* __restrict__ bsums) {
    __shared__ int lds[256];
    int b = blockIdx.x, t = threadIdx.x;
    int base = b * 1024 + t * 4;
    int v0 = 0, v1 = 0, v2 = 0, v3 = 0;
    if (base + 0 < NN) v0 = counts[base + 0];
    if (base + 1 < NN) v1 = counts[base + 1];
    if (base + 2 < NN) v2 = counts[base + 2];
    if (base + 3 < NN) v3 = counts[base + 3];
    int s = v0 + v1 + v2 + v3;
    lds[t] = s;
    __syncthreads();
    for (int off = 1; off < 256; off <<= 1) {
        int x = (t >= off) ? lds[t - off] : 0;
        __syncthreads();
        lds[t] += x;
        __syncthreads();
    }
    int run = lds[t] - s;
    if (t == 255) bsums[b] = lds[255];
    run += v0; if (base + 0 < NN) tmp[base + 0] = run;
    run += v1; if (base + 1 < NN) tmp[base + 1] = run;
    run += v2; if (base + 2 < NN) tmp[base + 2] = run;
    run += v3; if (base + 3 < NN) tmp[base + 3] = run;
}

__global__ void scan2(int* __restrict__ bsums) {
    if (threadIdx.x == 0) {
        int acc = 0;
        for (int i = 0; i < SCAN_NBLK; ++i) { int t = bsums[i]; bsums[i] = acc; acc += t; }
    }
}

__global__ __launch_bounds__(256) void scan3(const int* __restrict__ tmp,
                                             const int* __restrict__ bsums,
                                             const int* __restrict__ counts,
                                             int* __restrict__ rowptr,
                                             int* __restrict__ cursor) {
    int i = blockIdx.x * 256 + threadIdx.x;
    if (i >= NN) return;
    int incl = tmp[i] + bsums[i >> 10];
    rowptr[i + 1] = incl;
    cursor[i] = incl - counts[i];
    if (i == 0) rowptr[0] = 0;
}

__global__ __launch_bounds__(256) void edge_scatter(const int* __restrict__ ei,
                                                    int* __restrict__ cursor,
                                                    int* __restrict__ ssrc) {
    int e = blockIdx.x * 256 + threadIdx.x;
    if (e >= ETOT) return;
    int s, d;
    if (e < EE) { s = ei[e]; d = ei[EE + e]; } else { s = d = e - EE; }
    int pos = atomicAdd(&cursor[d], 1);
    ssrc[pos] = s;
}

// sort each row's sources ascending (deterministic 64-lane bitonic).
__global__ __launch_bounds__(256) void sort_rows(const int* __restrict__ rowptr,
                                                 int* __restrict__ ssrc) {
    int wid = (blockIdx.x * 256 + threadIdx.x) >> 6;
    int lane = threadIdx.x & 63;
    if (wid >= NN) return;
    int beg = rowptr[wid], end = rowptr[wid + 1];
    int L = end - beg;
    if (L > 64) return;
    int v = (lane < L) ? ssrc[beg + lane] : 0x7fffffff;
#pragma unroll
    for (int k = 2; k <= 64; k <<= 1) {
#pragma unroll
        for (int j = k >> 1; j > 0; j >>= 1) {
            int partner = __shfl_xor(v, j);
            bool up = ((lane & k) == 0);
            bool keepMin = (up == ((lane & j) == 0));
            int mn = min(v, partner), mx = max(v, partner);
            v = keepMin ? mn : mx;
        }
    }
    if (lane < L) ssrc[beg + lane] = v;
}

// ============================ weight / input prep (bf16) ============================

__global__ __launch_bounds__(256) void prep_wt(const float* __restrict__ Ws,
                                               unsigned short* __restrict__ WT) {
    int t = blockIdx.x * 256 + threadIdx.x;
    if (t >= LL * HH * HH) return;
    int l = t >> 16, rem = t & 65535;
    int n = rem >> 8, k = rem & 255;
    WT[t] = f2b(Ws[l * 65536 + k * HH + n]);
}

__global__ __launch_bounds__(256) void prep_inwt(const float* __restrict__ in_W,
                                                 unsigned short* __restrict__ WT) {
    int t = blockIdx.x * 256 + threadIdx.x;
    if (t >= HH * 64) return;
    int n = t >> 6, k = t & 63;
    WT[t] = (k < KIN) ? f2b(in_W[k * HH + n]) : 0;
}

__global__ __launch_bounds__(256) void prep_x(const float* __restrict__ x,
                                              unsigned short* __restrict__ xb) {
    int t = blockIdx.x * 256 + threadIdx.x;
    if (t >= NN * 64) return;
    int n = t >> 6, c = t & 63;
    xb[t] = (c < KIN) ? f2b(x[n * KIN + c]) : 0;
}

// ============================ MFMA GEMM  C = A @ Bt^T ============================
// tile 128x128x64, 4 waves (2x2), each wave 64x64 via 4x4 16x16x32 frags.
// ZHM=0: C row-major [M][256]. ZHM=1: C head-major zT[c>>5][row][c&31]
// (per-head 3.2MB slices, L2-resident for the head-affine aggregate).
// Launch with gridDim.y = HH/128 = 2 ALWAYS.
template<int ZHM>
__global__ __launch_bounds__(256) void gemm_mfma(const unsigned short* __restrict__ A,
                                                 const unsigned short* __restrict__ Bt,
                                                 unsigned short* __restrict__ C,
                                                 int M, int K) {
    __shared__ unsigned short As[128 * 64];
    __shared__ unsigned short Bs[128 * 64];
    int row0 = blockIdx.x * 128;
    int n0 = blockIdx.y * 128;
    int tid = threadIdx.x;
    int w = tid >> 6, l = tid & 63;
    int wm = w >> 1, wn = w & 1;
    int r15 = l & 15, q = l >> 4;

    f32x4 acc[4][4] = {};

    int crow = l >> 3;     // row within 8-row chunk
    int cs   = l & 7;      // 16B slot within row

    for (int kt = 0; kt < K; kt += 64) {
        if (kt) __syncthreads();
#pragma unroll
        for (int c = 0; c < 4; ++c) {
            int r = w * 32 + c * 8 + crow;          // tile row 0..127
            int sg = cs ^ (r & 7);                  // pre-swizzled source slot
            int ga = row0 + r; if (ga >= M) ga = M - 1;
            gload16(&A[(size_t)ga * K + kt + sg * 8], &As[(w * 32 + c * 8) * 64]);
            int gb = n0 + r;                        // < 256 always
            gload16(&Bt[(size_t)gb * K + kt + sg * 8], &Bs[(w * 32 + c * 8) * 64]);
        }
        __syncthreads();
#pragma unroll
        for (int kk = 0; kk < 2; ++kk) {
            bf16x8 aF[4], bF[4];
#pragma unroll
            for (int i = 0; i < 4; ++i) {
                int ar = wm * 64 + i * 16 + r15;
                aF[i] = *(bf16x8*)&As[ar * 64 + ((kk * 4 + q) ^ (ar & 7)) * 8];
                int br = wn * 64 + i * 16 + r15;
                bF[i] = *(bf16x8*)&Bs[br * 64 + ((kk * 4 + q) ^ (br & 7)) * 8];
            }
#pragma unroll
            for (int i = 0; i < 4; ++i)
#pragma unroll
                for (int j = 0; j < 4; ++j)
                    acc[i][j] = __builtin_amdgcn_mfma_f32_16x16x32_bf16(aF[i], bF[j], acc[i][j], 0, 0, 0);
        }
    }

    // C/D layout: col = lane&15, row = (lane>>4)*4 + reg
#pragma unroll
    for (int i = 0; i < 4; ++i)
#pragma unroll
        for (int j = 0; j < 4; ++j) {
            int nc = n0 + wn * 64 + j * 16 + r15;
#pragma unroll
            for (int r = 0; r < 4; ++r) {
                int gr = row0 + wm * 64 + i * 16 + q * 4 + r;
                if (gr < M) {
                    if (ZHM)
                        C[(size_t)(nc >> 5) * NN * CC + (size_t)gr * CC + (nc & 31)] = f2b(acc[i][j][r]);
                    else
                        C[(size_t)gr * HH + nc] = f2b(acc[i][j][r]);
                }
            }
        }
}

// ============================ attention scores (zT head-major) ============================
__global__ __launch_bounds__(256) void attn_scores(const unsigned short* __restrict__ zT,
                                                   const float* __restrict__ asrc,
                                                   const float* __restrict__ adst,
                                                   float* __restrict__ esrcT,
                                                   float* __restrict__ edstT) {
    int t = blockIdx.x * 256 + threadIdx.x;
    if (t >= NN * NH) return;
    int hd = t / NN, n = t - hd * NN;
    const unsigned short* zp = zT + (size_t)hd * NN * CC + (size_t)n * CC;
    const float* ap = asrc + hd * CC;
    const float* bp = adst + hd * CC;
    float s = 0.f, d = 0.f;
#pragma unroll
    for (int c = 0; c < CC; c += 4) {
        ushort4 zv = *(const ushort4*)(zp + c);
        float z0 = b2f(zv.x), z1 = b2f(zv.y), z2 = b2f(zv.z), z3 = b2f(zv.w);
        s += z0 * ap[c] + z1 * ap[c + 1] + z2 * ap[c + 2] + z3 * ap[c + 3];
        d += z0 * bp[c] + z1 * bp[c + 1] + z2 * bp[c + 2] + z3 * bp[c + 3];
    }
    esrcT[t] = s;   // t == hd*NN + n
    edstT[t] = d;
}

// ============================ head-affine aggregate v3 ============================
// blockIdx.x & 7 == head -> round-robin dispatch pins head hd's z-slice (3.2MB)
// + esrcT slice (200KB) in ONE XCD's 4MB L2. Block = 4 waves = 4 nodes, 1 head.
// Wave: 8 edge-groups x 8 lanes; lane loads 8B = 4 channels -> ~2 iterations per
// group at avg degree 17. 3-stage fixed butterfly combine -> deterministic.
// No max-subtraction needed (|e| <~ 16 << 88, fp32 exp range).
__global__ __launch_bounds__(256) void aggregate(const int* __restrict__ rowptr,
                                                 const int* __restrict__ ssrc,
                                                 const float* __restrict__ esrcT,
                                                 const float* __restrict__ edstT,
                                                 const unsigned short* __restrict__ zT,
                                                 unsigned short* __restrict__ outb) {
    int bid = blockIdx.x;
    int hd = bid & 7;
    int n = (bid >> 3) * 4 + (threadIdx.x >> 6);   // NN % 4 == 0 -> always < NN
    int lane = threadIdx.x & 63;
    int g = lane >> 3;                             // edge group 0..7
    int col = (lane & 7) * 4;                      // 4 channels
    const float* esp = esrcT + (size_t)hd * NN;
    const unsigned short* zp = zT + (size_t)hd * NN * CC;
    float ed = edstT[(size_t)hd * NN + n];
    int beg = rowptr[n], end = rowptr[n + 1];
    float a0 = 0.f, a1 = 0.f, a2 = 0.f, a3 = 0.f, den = 0.f;
    for (int i = beg + g; i < end; i += 8) {
        int s = ssrc[i];
        float es = esp[s];
        ushort4 zv = *(const ushort4*)&zp[(size_t)s * CC + col];
        float e = es + ed; e = (e > 0.f) ? e : 0.2f * e;
        float p = __expf(e);
        den += p;
        a0 += p * b2f(zv.x); a1 += p * b2f(zv.y);
        a2 += p * b2f(zv.z); a3 += p * b2f(zv.w);
    }
    // combine the 8 groups (butterfly over lane bits 3,4,5 — fixed order)
#pragma unroll
    for (int off = 8; off <= 32; off <<= 1) {
        a0 += __shfl_xor(a0, off); a1 += __shfl_xor(a1, off);
        a2 += __shfl_xor(a2, off); a3 += __shfl_xor(a3, off);
        den += __shfl_xor(den, off);
    }
    if (g == 0) {
        float inv = 1.f / den;                     // row nonempty (self loop)
        ushort4 o;
        o.x = f2b(a0 * inv); o.y = f2b(a1 * inv);
        o.z = f2b(a2 * inv); o.w = f2b(a3 * inv);
        *(ushort4*)&outb[(size_t)n * HH + hd * CC + col] = o;
    }
}

// ============================ BatchNorm ============================
__global__ __launch_bounds__(256) void col_stats(const unsigned short* __restrict__ X,
                                                 float* __restrict__ sums) {
    int c = threadIdx.x;
    int rows_per_block = (NN + gridDim.x - 1) / gridDim.x;
    int r0 = blockIdx.x * rows_per_block;
    int r1 = min(NN, r0 + rows_per_block);
    float s = 0.f, q = 0.f;
    for (int r = r0; r < r1; ++r) {
        float v = b2f(X[(size_t)r * HH + c]);
        s += v; q += v * v;
    }
    atomicAdd(&sums[c], s);
    atomicAdd(&sums[HH + c], q);
}

// out = relu((X-mean)*rstd*gamma+beta) [+ res]; all bf16; res/out may alias (same index).
__global__ __launch_bounds__(256) void bn_relu_add(const unsigned short* __restrict__ X,
                                                   const float* __restrict__ sums,
                                                   const float* __restrict__ gamma,
                                                   const float* __restrict__ beta,
                                                   const unsigned short* __restrict__ res,
                                                   unsigned short* __restrict__ outb) {
    int i = blockIdx.x * 256 + threadIdx.x;
    if (i >= NN * 64) return;
    int c4 = (i & 63) * 4;
    const float invN = 1.f / NN;
    ushort4 u = *(const ushort4*)(X + (size_t)i * 4);
    float v0 = b2f(u.x), v1 = b2f(u.y), v2 = b2f(u.z), v3 = b2f(u.w);
    float4 s1 = *(const float4*)&sums[c4];
    float4 s2 = *(const float4*)&sums[HH + c4];
    float4 gm = *(const float4*)&gamma[c4];
    float4 bt = *(const float4*)&beta[c4];
    float mn0 = s1.x * invN, mn1 = s1.y * invN, mn2 = s1.z * invN, mn3 = s1.w * invN;
    float rs0 = rsqrtf(fmaxf(s2.x * invN - mn0 * mn0, 0.f) + 1e-5f);
    float rs1 = rsqrtf(fmaxf(s2.y * invN - mn1 * mn1, 0.f) + 1e-5f);
    float rs2 = rsqrtf(fmaxf(s2.z * invN - mn2 * mn2, 0.f) + 1e-5f);
    float rs3 = rsqrtf(fmaxf(s2.w * invN - mn3 * mn3, 0.f) + 1e-5f);
    float r0 = fmaxf((v0 - mn0) * rs0 * gm.x + bt.x, 0.f);
    float r1 = fmaxf((v1 - mn1) * rs1 * gm.y + bt.y, 0.f);
    float r2 = fmaxf((v2 - mn2) * rs2 * gm.z + bt.z, 0.f);
    float r3 = fmaxf((v3 - mn3) * rs3 * gm.w + bt.w, 0.f);
    if (res) {
        ushort4 rv = *(const ushort4*)(res + (size_t)i * 4);
        r0 += b2f(rv.x); r1 += b2f(rv.y); r2 += b2f(rv.z); r3 += b2f(rv.w);
    }
    ushort4 ob;
    ob.x = f2b(r0); ob.y = f2b(r1); ob.z = f2b(r2); ob.w = f2b(r3);
    *(ushort4*)(outb + (size_t)i * 4) = ob;
}

// ============================ output projection (h bf16) ============================
__global__ __launch_bounds__(256) void out_proj(const unsigned short* __restrict__ h,
                                                const float* __restrict__ mW,
                                                const float* __restrict__ mb,
                                                const float* __restrict__ lW,
                                                const float* __restrict__ lb,
                                                float* __restrict__ out) {
    int wid = (blockIdx.x * 256 + threadIdx.x) >> 6;
    int lane = threadIdx.x & 63;
    if (wid >= NN) return;
    ushort4 hv = *(const ushort4*)&h[(size_t)wid * HH + lane * 4];
    float h0 = b2f(hv.x), h1 = b2f(hv.y), h2 = b2f(hv.z), h3 = b2f(hv.w);
    float4 wv = *(const float4*)&mW[lane * 4];
    float4 lv = *(const float4*)&lW[lane * 4];
    float sm = h0 * wv.x + h1 * wv.y + h2 * wv.z + h3 * wv.w;
    float sl = h0 * lv.x + h1 * lv.y + h2 * lv.z + h3 * lv.w;
    for (int off = 32; off > 0; off >>= 1) {
        sm += __shfl_down(sm, off);
        sl += __shfl_down(sl, off);
    }
    if (lane == 0) {
        out[wid] = sm + mb[0];
        float l = sl + lb[0];
        out[NN + wid] = fminf(10.f, fmaxf(-10.f, l));
    }
}

// ============================ launch ============================
extern "C" void kernel_launch(void* const* d_in, const int* in_sizes, int n_in,
                              void* d_out, int out_size, void* d_ws, size_t ws_size,
                              hipStream_t stream) {
    const float* x        = (const float*)d_in[0];
    const int*   ei       = (const int*)d_in[1];
    const float* in_W     = (const float*)d_in[2];
    const float* in_gamma = (const float*)d_in[4];
    const float* in_beta  = (const float*)d_in[5];
    const float* Ws       = (const float*)d_in[6];
    const float* att_src  = (const float*)d_in[7];
    const float* att_dst  = (const float*)d_in[8];
    const float* bn_gamma = (const float*)d_in[10];
    const float* bn_beta  = (const float*)d_in[11];
    const float* mean_W   = (const float*)d_in[12];
    const float* mean_b   = (const float*)d_in[13];
    const float* lv_W     = (const float*)d_in[14];
    const float* lv_b     = (const float*)d_in[15];
    float* out = (float*)d_out;

    // workspace layout (bytes)
    char* p = (char*)d_ws;
    unsigned short* z    = (unsigned short*)p; p += (size_t)NN * HH * 2;   // zT for layers
    unsigned short* hb   = (unsigned short*)p; p += (size_t)NN * HH * 2;
    unsigned short* aggb = (unsigned short*)p; p += (size_t)NN * HH * 2;
    float* esrcT = (float*)p;                  p += (size_t)NN * NH * 4;
    float* edstT = (float*)p;                  p += (size_t)NN * NH * 4;
    float* sums = (float*)p;                   p += 512 * 4;
    unsigned short* WT   = (unsigned short*)p; p += (size_t)LL * HH * HH * 2;
    unsigned short* inWT = (unsigned short*)p; p += (size_t)HH * 64 * 2;
    int* counts = (int*)p;                     p += (size_t)NN * 4;
    int* rowptr = (int*)p;                     p += (size_t)(NN + 1) * 4;
    int* cursor = (int*)p;                     p += (size_t)NN * 4;
    int* ssrc   = (int*)p;                     p += (size_t)ETOT * 4;
    int* bsums  = (int*)p;                     p += 64 * 4;
    unsigned short* xb = aggb;  // alias: xb dead before aggb first written

    // ---- CSR build (+ per-row source sort: locality + canonical order) ----
    hipMemsetAsync(counts, 0, NN * sizeof(int), stream);
    edge_hist<<<(ETOT + 255) / 256, 256, 0, stream>>>(ei, counts);
    scan1<<<SCAN_NBLK, 256, 0, stream>>>(counts, cursor, bsums);
    scan2<<<1, 64, 0, stream>>>(bsums);
    scan3<<<(NN + 255) / 256, 256, 0, stream>>>(cursor, bsums, counts, rowptr, cursor);
    edge_scatter<<<(ETOT + 255) / 256, 256, 0, stream>>>(ei, cursor, ssrc);
    sort_rows<<<(NN * 64 + 255) / 256, 256, 0, stream>>>(rowptr, ssrc);

    // ---- bf16 prep ----
    prep_wt<<<(LL * HH * HH + 255) / 256, 256, 0, stream>>>(Ws, WT);
    prep_inwt<<<(HH * 64 + 255) / 256, 256, 0, stream>>>(in_W, inWT);
    prep_x<<<(NN * 64 + 255) / 256, 256, 0, stream>>>(x, xb);

    // ---- input projection + BN + ReLU (row-major z: feeds only BN chain) ----
    {
        dim3 g((NN + 127) / 128, 2);
        gemm_mfma<0><<<g, 256, 0, stream>>>(xb, inWT, z, NN, 64);
    }
    hipMemsetAsync(sums, 0, 512 * sizeof(float), stream);
    col_stats<<<1024, 256, 0, stream>>>(z, sums);
    bn_relu_add<<<(NN * 64 + 255) / 256, 256, 0, stream>>>(z, sums, in_gamma, in_beta,
                                                           nullptr, hb);

    // ---- GAT layers ----
    for (int l = 0; l < LL; ++l) {
        const unsigned short* WTl = WT + (size_t)l * HH * HH;
        const float* asl = att_src + (size_t)l * NH * CC;
        const float* adl = att_dst + (size_t)l * NH * CC;
        const float* gl  = bn_gamma + (size_t)l * HH;
        const float* bl  = bn_beta + (size_t)l * HH;

        dim3 g((NN + 127) / 128, 2);
        gemm_mfma<1><<<g, 256, 0, stream>>>(hb, WTl, z, NN, HH);       // z head-major
        attn_scores<<<(NN * NH + 255) / 256, 256, 0, stream>>>(z, asl, adl, esrcT, edstT);
        aggregate<<<(NN / 4) * 8, 256, 0, stream>>>(rowptr, ssrc, esrcT, edstT, z, aggb);
        hipMemsetAsync(sums, 0, 512 * sizeof(float), stream);
        col_stats<<<1024, 256, 0, stream>>>(aggb, sums);
        bn_relu_add<<<(NN * 64 + 255) / 256, 256, 0, stream>>>(aggb, sums, gl, bl, hb, hb);
    }

    // ---- output heads ----
    out_proj<<<(NN * 64 + 255) / 256, 256, 0, stream>>>(hb, mean_W, mean_b, lv_W, lv_b, out);
}

// Round 9
// 875.418 us; speedup vs baseline: 1.4056x; 1.2230x over previous
//
#include <hip/hip_runtime.h>

#define NN 50000
#define EE 800000
#define ETOT 850000
#define KIN 61
#define HH 256
#define NH 8
#define CC 32
#define LL 4
#define SCAN_NBLK 49   // ceil(NN/1024)

typedef __attribute__((ext_vector_type(8))) short bf16x8;
typedef __attribute__((ext_vector_type(4))) float f32x4;

__device__ __forceinline__ unsigned short f2b(float f) {
    unsigned u = __builtin_bit_cast(unsigned, f);
    u += 0x7fffu + ((u >> 16) & 1u);   // RNE
    return (unsigned short)(u >> 16);
}
__device__ __forceinline__ float b2f(unsigned short h) {
    unsigned u = ((unsigned)h) << 16;
    return __builtin_bit_cast(float, u);
}

// async global->LDS, 16B per lane; LDS dest is wave-uniform base + lane*16
__device__ __forceinline__ void gload16(const void* g, void* l) {
    __builtin_amdgcn_global_load_lds(
        (const __attribute__((address_space(1))) void*)g,
        (__attribute__((address_space(3))) void*)l, 16, 0, 0);
}

// ============================ CSR build ============================

__global__ __launch_bounds__(256) void edge_hist(const int* __restrict__ ei,
                                                 int* __restrict__ counts) {
    int e = blockIdx.x * 256 + threadIdx.x;
    if (e >= ETOT) return;
    int d = (e < EE) ? ei[EE + e] : (e - EE);
    atomicAdd(&counts[d], 1);
}

__global__ __launch_bounds__(256) void scan1(const int* __restrict__ counts,
                                             int* __restrict__ tmp,
                                             int* __restrict__ bsums) {
    __shared__ int lds[256];
    int b = blockIdx.x, t = threadIdx.x;
    int base = b * 1024 + t * 4;
    int v0 = 0, v1 = 0, v2 = 0, v3 = 0;
    if (base + 0 < NN) v0 = counts[base + 0];
    if (base + 1 < NN) v1 = counts[base + 1];
    if (base + 2 < NN) v2 = counts[base + 2];
    if (base + 3 < NN) v3 = counts[base + 3];
    int s = v0 + v1 + v2 + v3;
    lds[t] = s;
    __syncthreads();
    for (int off = 1; off < 256; off <<= 1) {
        int x = (t >= off) ? lds[t - off] : 0;
        __syncthreads();
        lds[t] += x;
        __syncthreads();
    }
    int run = lds[t] - s;
    if (t == 255) bsums[b] = lds[255];
    run += v0; if (base + 0 < NN) tmp[base + 0] = run;
    run += v1; if (base + 1 < NN) tmp[base + 1] = run;
    run += v2; if (base + 2 < NN) tmp[base + 2] = run;
    run += v3; if (base + 3 < NN) tmp[base + 3] = run;
}

__global__ void scan2(int* __restrict__ bsums) {
    if (threadIdx.x == 0) {
        int acc = 0;
        for (int i = 0; i < SCAN_NBLK; ++i) { int t = bsums[i]; bsums[i] = acc; acc += t; }
    }
}

__global__ __launch_bounds__(256) void scan3(const int* __restrict__ tmp,
                                             const int* __restrict__ bsums,
                                             const int* __restrict__ counts,
                                             int* __restrict__ rowptr,
                                             int* __restrict__ cursor) {
    int i = blockIdx.x * 256 + threadIdx.x;
    if (i >= NN) return;
    int incl = tmp[i] + bsums[i >> 10];
    rowptr[i + 1] = incl;
    cursor[i] = incl - counts[i];
    if (i == 0) rowptr[0] = 0;
}

__global__ __launch_bounds__(256) void edge_scatter(const int* __restrict__ ei,
                                                    int* __restrict__ cursor,
                                                    int* __restrict__ ssrc) {
    int e = blockIdx.x * 256 + threadIdx.x;
    if (e >= ETOT) return;
    int s, d;
    if (e < EE) { s = ei[e]; d = ei[EE + e]; } else { s = d = e - EE; }
    int pos = atomicAdd(&cursor[d], 1);
    ssrc[pos] = s;
}

// sort each row's sources ascending (deterministic 64-lane bitonic).
__global__ __launch_bounds__(256) void sort_rows(const int* __restrict__ rowptr,
                                                 int* __restrict__ ssrc) {
    int wid = (blockIdx.x * 256 + threadIdx.x) >> 6;
    int lane = threadIdx.x & 63;
    if (wid >= NN) return;
    int beg = rowptr[wid], end = rowptr[wid + 1];
    int L = end - beg;
    if (L > 64) return;
    int v = (lane < L) ? ssrc[beg + lane] : 0x7fffffff;
#pragma unroll
    for (int k = 2; k <= 64; k <<= 1) {
#pragma unroll
        for (int j = k >> 1; j > 0; j >>= 1) {
            int partner = __shfl_xor(v, j);
            bool up = ((lane & k) == 0);
            bool keepMin = (up == ((lane & j) == 0));
            int mn = min(v, partner), mx = max(v, partner);
            v = keepMin ? mn : mx;
        }
    }
    if (lane < L) ssrc[beg + lane] = v;
}

// ============================ weight / input prep (bf16) ============================

__global__ __launch_bounds__(256) void prep_wt(const float* __restrict__ Ws,
                                               unsigned short* __restrict__ WT) {
    int t = blockIdx.x * 256 + threadIdx.x;
    if (t >= LL * HH * HH) return;
    int l = t >> 16, rem = t & 65535;
    int n = rem >> 8, k = rem & 255;
    WT[t] = f2b(Ws[l * 65536 + k * HH + n]);
}

__global__ __launch_bounds__(256) void prep_inwt(const float* __restrict__ in_W,
                                                 unsigned short* __restrict__ WT) {
    int t = blockIdx.x * 256 + threadIdx.x;
    if (t >= HH * 64) return;
    int n = t >> 6, k = t & 63;
    WT[t] = (k < KIN) ? f2b(in_W[k * HH + n]) : 0;
}

__global__ __launch_bounds__(256) void prep_x(const float* __restrict__ x,
                                              unsigned short* __restrict__ xb) {
    int t = blockIdx.x * 256 + threadIdx.x;
    if (t >= NN * 64) return;
    int n = t >> 6, c = t & 63;
    xb[t] = (c < KIN) ? f2b(x[n * KIN + c]) : 0;
}

// ============================ MFMA GEMM  C = A @ Bt^T ============================
// tile 128x128x64, 4 waves (2x2), each wave 64x64 via 4x4 16x16x32 frags.
// ZHM=0: C row-major [M][256]. ZHM=1: C head-major zT[c>>5][row][c&31]
// (per-head 3.2MB slices, L2-resident for the head-affine aggregate).
// Launch with gridDim.y = HH/128 = 2 ALWAYS.
template<int ZHM>
__global__ __launch_bounds__(256) void gemm_mfma(const unsigned short* __restrict__ A,
                                                 const unsigned short* __restrict__ Bt,
                                                 unsigned short* __restrict__ C,
                                                 int M, int K) {
    __shared__ unsigned short As[128 * 64];
    __shared__ unsigned short Bs[128 * 64];
    int row0 = blockIdx.x * 128;
    int n0 = blockIdx.y * 128;
    int tid = threadIdx.x;
    int w = tid >> 6, l = tid & 63;
    int wm = w >> 1, wn = w & 1;
    int r15 = l & 15, q = l >> 4;

    f32x4 acc[4][4] = {};

    int crow = l >> 3;     // row within 8-row chunk
    int cs   = l & 7;      // 16B slot within row

    for (int kt = 0; kt < K; kt += 64) {
        if (kt) __syncthreads();
#pragma unroll
        for (int c = 0; c < 4; ++c) {
            int r = w * 32 + c * 8 + crow;          // tile row 0..127
            int sg = cs ^ (r & 7);                  // pre-swizzled source slot
            int ga = row0 + r; if (ga >= M) ga = M - 1;
            gload16(&A[(size_t)ga * K + kt + sg * 8], &As[(w * 32 + c * 8) * 64]);
            int gb = n0 + r;                        // < 256 always
            gload16(&Bt[(size_t)gb * K + kt + sg * 8], &Bs[(w * 32 + c * 8) * 64]);
        }
        __syncthreads();
#pragma unroll
        for (int kk = 0; kk < 2; ++kk) {
            bf16x8 aF[4], bF[4];
#pragma unroll
            for (int i = 0; i < 4; ++i) {
                int ar = wm * 64 + i * 16 + r15;
                aF[i] = *(bf16x8*)&As[ar * 64 + ((kk * 4 + q) ^ (ar & 7)) * 8];
                int br = wn * 64 + i * 16 + r15;
                bF[i] = *(bf16x8*)&Bs[br * 64 + ((kk * 4 + q) ^ (br & 7)) * 8];
            }
#pragma unroll
            for (int i = 0; i < 4; ++i)
#pragma unroll
                for (int j = 0; j < 4; ++j)
                    acc[i][j] = __builtin_amdgcn_mfma_f32_16x16x32_bf16(aF[i], bF[j], acc[i][j], 0, 0, 0);
        }
    }

    // C/D layout: col = lane&15, row = (lane>>4)*4 + reg
#pragma unroll
    for (int i = 0; i < 4; ++i)
#pragma unroll
        for (int j = 0; j < 4; ++j) {
            int nc = n0 + wn * 64 + j * 16 + r15;
#pragma unroll
            for (int r = 0; r < 4; ++r) {
                int gr = row0 + wm * 64 + i * 16 + q * 4 + r;
                if (gr < M) {
                    if (ZHM)
                        C[(size_t)(nc >> 5) * NN * CC + (size_t)gr * CC + (nc & 31)] = f2b(acc[i][j][r]);
                    else
                        C[(size_t)gr * HH + nc] = f2b(acc[i][j][r]);
                }
            }
        }
}

// ============================ attention scores (zT head-major) ============================
__global__ __launch_bounds__(256) void attn_scores(const unsigned short* __restrict__ zT,
                                                   const float* __restrict__ asrc,
                                                   const float* __restrict__ adst,
                                                   float* __restrict__ esrcT,
                                                   float* __restrict__ edstT) {
    int t = blockIdx.x * 256 + threadIdx.x;
    if (t >= NN * NH) return;
    int hd = t / NN, n = t - hd * NN;
    const unsigned short* zp = zT + (size_t)hd * NN * CC + (size_t)n * CC;
    const float* ap = asrc + hd * CC;
    const float* bp = adst + hd * CC;
    float s = 0.f, d = 0.f;
#pragma unroll
    for (int c = 0; c < CC; c += 4) {
        ushort4 zv = *(const ushort4*)(zp + c);
        float z0 = b2f(zv.x), z1 = b2f(zv.y), z2 = b2f(zv.z), z3 = b2f(zv.w);
        s += z0 * ap[c] + z1 * ap[c + 1] + z2 * ap[c + 2] + z3 * ap[c + 3];
        d += z0 * bp[c] + z1 * bp[c + 1] + z2 * bp[c + 2] + z3 * bp[c + 3];
    }
    esrcT[t] = s;   // t == hd*NN + n
    edstT[t] = d;
}

// ============================ head-affine aggregate v4 ============================
// blockIdx.x & 7 == head -> round-robin dispatch pins head hd's z-slice (3.2MB)
// + esrcT slice (200KB) in ONE XCD's 4MB L2.
// Block = 32 nodes x 1 head: 4 waves x 8 groups; each 8-lane GROUP owns ONE node
// and walks its full sorted edge list serially (~17 trips, 2-way unrolled ILP).
// den + accumulators are group-local -> NO cross-lane combines; each lane ends
// holding its 4 output channels. Deterministic (sorted order, fixed unroll).
// No max-subtraction needed (|e| <~ 16 << 88, fp32 exp range).
__global__ __launch_bounds__(256) void aggregate(const int* __restrict__ rowptr,
                                                 const int* __restrict__ ssrc,
                                                 const float* __restrict__ esrcT,
                                                 const float* __restrict__ edstT,
                                                 const unsigned short* __restrict__ zT,
                                                 unsigned short* __restrict__ outb) {
    int bid = blockIdx.x;
    int hd = bid & 7;
    int nb = bid >> 3;                              // node-block of 32
    int lane = threadIdx.x & 63;
    int wv = threadIdx.x >> 6;
    int g = lane >> 3;                              // group 0..7 -> node
    int n = nb * 32 + wv * 8 + g;
    int col = (lane & 7) * 4;                       // 4 channels of this head
    bool act = n < NN;
    const float* esp = esrcT + (size_t)hd * NN;
    const unsigned short* zp = zT + (size_t)hd * NN * CC;
    float ed = act ? edstT[(size_t)hd * NN + n] : 0.f;
    int beg = act ? rowptr[n] : 0;
    int end = act ? rowptr[n + 1] : 0;
    float den0 = 0.f, den1 = 0.f;
    float a0 = 0.f, a1 = 0.f, a2 = 0.f, a3 = 0.f;
    float b0 = 0.f, b1 = 0.f, b2 = 0.f, b3 = 0.f;
    int i = beg;
    for (; i + 1 < end; i += 2) {
        int s0 = ssrc[i], s1 = ssrc[i + 1];
        float es0 = esp[s0], es1 = esp[s1];
        ushort4 z0 = *(const ushort4*)&zp[(size_t)s0 * CC + col];
        ushort4 z1 = *(const ushort4*)&zp[(size_t)s1 * CC + col];
        float e0 = es0 + ed; e0 = (e0 > 0.f) ? e0 : 0.2f * e0;
        float e1 = es1 + ed; e1 = (e1 > 0.f) ? e1 : 0.2f * e1;
        float p0 = __expf(e0);
        float p1 = __expf(e1);
        den0 += p0;
        a0 += p0 * b2f(z0.x); a1 += p0 * b2f(z0.y);
        a2 += p0 * b2f(z0.z); a3 += p0 * b2f(z0.w);
        den1 += p1;
        b0 += p1 * b2f(z1.x); b1 += p1 * b2f(z1.y);
        b2 += p1 * b2f(z1.z); b3 += p1 * b2f(z1.w);
    }
    if (i < end) {
        int s0 = ssrc[i];
        float es0 = esp[s0];
        ushort4 z0 = *(const ushort4*)&zp[(size_t)s0 * CC + col];
        float e0 = es0 + ed; e0 = (e0 > 0.f) ? e0 : 0.2f * e0;
        float p0 = __expf(e0);
        den0 += p0;
        a0 += p0 * b2f(z0.x); a1 += p0 * b2f(z0.y);
        a2 += p0 * b2f(z0.z); a3 += p0 * b2f(z0.w);
    }
    if (act) {
        float inv = 1.f / (den0 + den1);            // row nonempty (self loop)
        ushort4 o;
        o.x = f2b((a0 + b0) * inv); o.y = f2b((a1 + b1) * inv);
        o.z = f2b((a2 + b2) * inv); o.w = f2b((a3 + b3) * inv);
        *(ushort4*)&outb[(size_t)n * HH + hd * CC + col] = o;
    }
}

// ============================ BatchNorm ============================
__global__ __launch_bounds__(256) void col_stats(const unsigned short* __restrict__ X,
                                                 float* __restrict__ sums) {
    int c = threadIdx.x;
    int rows_per_block = (NN + gridDim.x - 1) / gridDim.x;
    int r0 = blockIdx.x * rows_per_block;
    int r1 = min(NN, r0 + rows_per_block);
    float s = 0.f, q = 0.f;
    for (int r = r0; r < r1; ++r) {
        float v = b2f(X[(size_t)r * HH + c]);
        s += v; q += v * v;
    }
    atomicAdd(&sums[c], s);
    atomicAdd(&sums[HH + c], q);
}

// out = relu((X-mean)*rstd*gamma+beta) [+ res]; all bf16; res/out may alias (same index).
__global__ __launch_bounds__(256) void bn_relu_add(const unsigned short* __restrict__ X,
                                                   const float* __restrict__ sums,
                                                   const float* __restrict__ gamma,
                                                   const float* __restrict__ beta,
                                                   const unsigned short* __restrict__ res,
                                                   unsigned short* __restrict__ outb) {
    int i = blockIdx.x * 256 + threadIdx.x;
    if (i >= NN * 64) return;
    int c4 = (i & 63) * 4;
    const float invN = 1.f / NN;
    ushort4 u = *(const ushort4*)(X + (size_t)i * 4);
    float v0 = b2f(u.x), v1 = b2f(u.y), v2 = b2f(u.z), v3 = b2f(u.w);
    float4 s1 = *(const float4*)&sums[c4];
    float4 s2 = *(const float4*)&sums[HH + c4];
    float4 gm = *(const float4*)&gamma[c4];
    float4 bt = *(const float4*)&beta[c4];
    float mn0 = s1.x * invN, mn1 = s1.y * invN, mn2 = s1.z * invN, mn3 = s1.w * invN;
    float rs0 = rsqrtf(fmaxf(s2.x * invN - mn0 * mn0, 0.f) + 1e-5f);
    float rs1 = rsqrtf(fmaxf(s2.y * invN - mn1 * mn1, 0.f) + 1e-5f);
    float rs2 = rsqrtf(fmaxf(s2.z * invN - mn2 * mn2, 0.f) + 1e-5f);
    float rs3 = rsqrtf(fmaxf(s2.w * invN - mn3 * mn3, 0.f) + 1e-5f);
    float r0 = fmaxf((v0 - mn0) * rs0 * gm.x + bt.x, 0.f);
    float r1 = fmaxf((v1 - mn1) * rs1 * gm.y + bt.y, 0.f);
    float r2 = fmaxf((v2 - mn2) * rs2 * gm.z + bt.z, 0.f);
    float r3 = fmaxf((v3 - mn3) * rs3 * gm.w + bt.w, 0.f);
    if (res) {
        ushort4 rv = *(const ushort4*)(res + (size_t)i * 4);
        r0 += b2f(rv.x); r1 += b2f(rv.y); r2 += b2f(rv.z); r3 += b2f(rv.w);
    }
    ushort4 ob;
    ob.x = f2b(r0); ob.y = f2b(r1); ob.z = f2b(r2); ob.w = f2b(r3);
    *(ushort4*)(outb + (size_t)i * 4) = ob;
}

// ============================ output projection (h bf16) ============================
__global__ __launch_bounds__(256) void out_proj(const unsigned short* __restrict__ h,
                                                const float* __restrict__ mW,
                                                const float* __restrict__ mb,
                                                const float* __restrict__ lW,
                                                const float* __restrict__ lb,
                                                float* __restrict__ out) {
    int wid = (blockIdx.x * 256 + threadIdx.x) >> 6;
    int lane = threadIdx.x & 63;
    if (wid >= NN) return;
    ushort4 hv = *(const ushort4*)&h[(size_t)wid * HH + lane * 4];
    float h0 = b2f(hv.x), h1 = b2f(hv.y), h2 = b2f(hv.z), h3 = b2f(hv.w);
    float4 wv = *(const float4*)&mW[lane * 4];
    float4 lv = *(const float4*)&lW[lane * 4];
    float sm = h0 * wv.x + h1 * wv.y + h2 * wv.z + h3 * wv.w;
    float sl = h0 * lv.x + h1 * lv.y + h2 * lv.z + h3 * lv.w;
    for (int off = 32; off > 0; off >>= 1) {
        sm += __shfl_down(sm, off);
        sl += __shfl_down(sl, off);
    }
    if (lane == 0) {
        out[wid] = sm + mb[0];
        float l = sl + lb[0];
        out[NN + wid] = fminf(10.f, fmaxf(-10.f, l));
    }
}

// ============================ launch ============================
extern "C" void kernel_launch(void* const* d_in, const int* in_sizes, int n_in,
                              void* d_out, int out_size, void* d_ws, size_t ws_size,
                              hipStream_t stream) {
    const float* x        = (const float*)d_in[0];
    const int*   ei       = (const int*)d_in[1];
    const float* in_W     = (const float*)d_in[2];
    const float* in_gamma = (const float*)d_in[4];
    const float* in_beta  = (const float*)d_in[5];
    const float* Ws       = (const float*)d_in[6];
    const float* att_src  = (const float*)d_in[7];
    const float* att_dst  = (const float*)d_in[8];
    const float* bn_gamma = (const float*)d_in[10];
    const float* bn_beta  = (const float*)d_in[11];
    const float* mean_W   = (const float*)d_in[12];
    const float* mean_b   = (const float*)d_in[13];
    const float* lv_W     = (const float*)d_in[14];
    const float* lv_b     = (const float*)d_in[15];
    float* out = (float*)d_out;

    // workspace layout (bytes)
    char* p = (char*)d_ws;
    unsigned short* z    = (unsigned short*)p; p += (size_t)NN * HH * 2;   // zT for layers
    unsigned short* hb   = (unsigned short*)p; p += (size_t)NN * HH * 2;
    unsigned short* aggb = (unsigned short*)p; p += (size_t)NN * HH * 2;
    float* esrcT = (float*)p;                  p += (size_t)NN * NH * 4;
    float* edstT = (float*)p;                  p += (size_t)NN * NH * 4;
    float* sums = (float*)p;                   p += 512 * 4;
    unsigned short* WT   = (unsigned short*)p; p += (size_t)LL * HH * HH * 2;
    unsigned short* inWT = (unsigned short*)p; p += (size_t)HH * 64 * 2;
    int* counts = (int*)p;                     p += (size_t)NN * 4;
    int* rowptr = (int*)p;                     p += (size_t)(NN + 1) * 4;
    int* cursor = (int*)p;                     p += (size_t)NN * 4;
    int* ssrc   = (int*)p;                     p += (size_t)ETOT * 4;
    int* bsums  = (int*)p;                     p += 64 * 4;
    unsigned short* xb = aggb;  // alias: xb dead before aggb first written

    // ---- CSR build (+ per-row source sort: locality + canonical order) ----
    hipMemsetAsync(counts, 0, NN * sizeof(int), stream);
    edge_hist<<<(ETOT + 255) / 256, 256, 0, stream>>>(ei, counts);
    scan1<<<SCAN_NBLK, 256, 0, stream>>>(counts, cursor, bsums);
    scan2<<<1, 64, 0, stream>>>(bsums);
    scan3<<<(NN + 255) / 256, 256, 0, stream>>>(cursor, bsums, counts, rowptr, cursor);
    edge_scatter<<<(ETOT + 255) / 256, 256, 0, stream>>>(ei, cursor, ssrc);
    sort_rows<<<(NN * 64 + 255) / 256, 256, 0, stream>>>(rowptr, ssrc);

    // ---- bf16 prep ----
    prep_wt<<<(LL * HH * HH + 255) / 256, 256, 0, stream>>>(Ws, WT);
    prep_inwt<<<(HH * 64 + 255) / 256, 256, 0, stream>>>(in_W, inWT);
    prep_x<<<(NN * 64 + 255) / 256, 256, 0, stream>>>(x, xb);

    // ---- input projection + BN + ReLU (row-major z: feeds only BN chain) ----
    {
        dim3 g((NN + 127) / 128, 2);
        gemm_mfma<0><<<g, 256, 0, stream>>>(xb, inWT, z, NN, 64);
    }
    hipMemsetAsync(sums, 0, 512 * sizeof(float), stream);
    col_stats<<<1024, 256, 0, stream>>>(z, sums);
    bn_relu_add<<<(NN * 64 + 255) / 256, 256, 0, stream>>>(z, sums, in_gamma, in_beta,
                                                           nullptr, hb);

    // ---- GAT layers ----
    for (int l = 0; l < LL; ++l) {
        const unsigned short* WTl = WT + (size_t)l * HH * HH;
        const float* asl = att_src + (size_t)l * NH * CC;
        const float* adl = att_dst + (size_t)l * NH * CC;
        const float* gl  = bn_gamma + (size_t)l * HH;
        const float* bl  = bn_beta + (size_t)l * HH;

        dim3 g((NN + 127) / 128, 2);
        gemm_mfma<1><<<g, 256, 0, stream>>>(hb, WTl, z, NN, HH);       // z head-major
        attn_scores<<<(NN * NH + 255) / 256, 256, 0, stream>>>(z, asl, adl, esrcT, edstT);
        aggregate<<<((NN + 31) / 32) * 8, 256, 0, stream>>>(rowptr, ssrc, esrcT, edstT, z, aggb);
        hipMemsetAsync(sums, 0, 512 * sizeof(float), stream);
        col_stats<<<1024, 256, 0, stream>>>(aggb, sums);
        bn_relu_add<<<(NN * 64 + 255) / 256, 256, 0, stream>>>(aggb, sums, gl, bl, hb, hb);
    }

    // ---- output heads ----
    out_proj<<<(NN * 64 + 255) / 256, 256, 0, stream>>>(hb, mean_W, mean_b, lv_W, lv_b, out);
}

// Round 10
// 829.725 us; speedup vs baseline: 1.4830x; 1.0551x over previous
//
#include <hip/hip_runtime.h>

#define NN 50000
#define EE 800000
#define ETOT 850000
#define KIN 61
#define HH 256
#define NH 8
#define CC 32
#define LL 4
#define SCAN_NBLK 49   // ceil(NN/1024)

typedef __attribute__((ext_vector_type(8))) short bf16x8;
typedef __attribute__((ext_vector_type(4))) float f32x4;

__device__ __forceinline__ unsigned short f2b(float f) {
    unsigned u = __builtin_bit_cast(unsigned, f);
    u += 0x7fffu + ((u >> 16) & 1u);   // RNE
    return (unsigned short)(u >> 16);
}
__device__ __forceinline__ float b2f(unsigned short h) {
    unsigned u = ((unsigned)h) << 16;
    return __builtin_bit_cast(float, u);
}

// async global->LDS, 16B per lane; LDS dest is wave-uniform base + lane*16
__device__ __forceinline__ void gload16(const void* g, void* l) {
    __builtin_amdgcn_global_load_lds(
        (const __attribute__((address_space(1))) void*)g,
        (__attribute__((address_space(3))) void*)l, 16, 0, 0);
}

// ============================ CSR build ============================

__global__ __launch_bounds__(256) void edge_hist(const int* __restrict__ ei,
                                                 int* __restrict__ counts) {
    int e = blockIdx.x * 256 + threadIdx.x;
    if (e >= ETOT) return;
    int d = (e < EE) ? ei[EE + e] : (e - EE);
    atomicAdd(&counts[d], 1);
}

__global__ __launch_bounds__(256) void scan1(const int* __restrict__ counts,
                                             int* __restrict__ tmp,
                                             int* __restrict__ bsums) {
    __shared__ int lds[256];
    int b = blockIdx.x, t = threadIdx.x;
    int base = b * 1024 + t * 4;
    int v0 = 0, v1 = 0, v2 = 0, v3 = 0;
    if (base + 0 < NN) v0 = counts[base + 0];
    if (base + 1 < NN) v1 = counts[base + 1];
    if (base + 2 < NN) v2 = counts[base + 2];
    if (base + 3 < NN) v3 = counts[base + 3];
    int s = v0 + v1 + v2 + v3;
    lds[t] = s;
    __syncthreads();
    for (int off = 1; off < 256; off <<= 1) {
        int x = (t >= off) ? lds[t - off] : 0;
        __syncthreads();
        lds[t] += x;
        __syncthreads();
    }
    int run = lds[t] - s;
    if (t == 255) bsums[b] = lds[255];
    run += v0; if (base + 0 < NN) tmp[base + 0] = run;
    run += v1; if (base + 1 < NN) tmp[base + 1] = run;
    run += v2; if (base + 2 < NN) tmp[base + 2] = run;
    run += v3; if (base + 3 < NN) tmp[base + 3] = run;
}

__global__ void scan2(int* __restrict__ bsums) {
    if (threadIdx.x == 0) {
        int acc = 0;
        for (int i = 0; i < SCAN_NBLK; ++i) { int t = bsums[i]; bsums[i] = acc; acc += t; }
    }
}

__global__ __launch_bounds__(256) void scan3(const int* __restrict__ tmp,
                                             const int* __restrict__ bsums,
                                             const int* __restrict__ counts,
                                             int* __restrict__ rowptr,
                                             int* __restrict__ cursor) {
    int i = blockIdx.x * 256 + threadIdx.x;
    if (i >= NN) return;
    int incl = tmp[i] + bsums[i >> 10];
    rowptr[i + 1] = incl;
    cursor[i] = incl - counts[i];
    if (i == 0) rowptr[0] = 0;
}

__global__ __launch_bounds__(256) void edge_scatter(const int* __restrict__ ei,
                                                    int* __restrict__ cursor,
                                                    int* __restrict__ ssrc) {
    int e = blockIdx.x * 256 + threadIdx.x;
    if (e >= ETOT) return;
    int s, d;
    if (e < EE) { s = ei[e]; d = ei[EE + e]; } else { s = d = e - EE; }
    int pos = atomicAdd(&cursor[d], 1);
    ssrc[pos] = s;
}

// sort each row's sources ascending (deterministic 64-lane bitonic).
__global__ __launch_bounds__(256) void sort_rows(const int* __restrict__ rowptr,
                                                 int* __restrict__ ssrc) {
    int wid = (blockIdx.x * 256 + threadIdx.x) >> 6;
    int lane = threadIdx.x & 63;
    if (wid >= NN) return;
    int beg = rowptr[wid], end = rowptr[wid + 1];
    int L = end - beg;
    if (L > 64) return;
    int v = (lane < L) ? ssrc[beg + lane] : 0x7fffffff;
#pragma unroll
    for (int k = 2; k <= 64; k <<= 1) {
#pragma unroll
        for (int j = k >> 1; j > 0; j >>= 1) {
            int partner = __shfl_xor(v, j);
            bool up = ((lane & k) == 0);
            bool keepMin = (up == ((lane & j) == 0));
            int mn = min(v, partner), mx = max(v, partner);
            v = keepMin ? mn : mx;
        }
    }
    if (lane < L) ssrc[beg + lane] = v;
}

// ============================ weight / input prep (bf16) ============================

__global__ __launch_bounds__(256) void prep_wt(const float* __restrict__ Ws,
                                               unsigned short* __restrict__ WT) {
    int t = blockIdx.x * 256 + threadIdx.x;
    if (t >= LL * HH * HH) return;
    int l = t >> 16, rem = t & 65535;
    int n = rem >> 8, k = rem & 255;
    WT[t] = f2b(Ws[l * 65536 + k * HH + n]);
}

__global__ __launch_bounds__(256) void prep_inwt(const float* __restrict__ in_W,
                                                 unsigned short* __restrict__ WT) {
    int t = blockIdx.x * 256 + threadIdx.x;
    if (t >= HH * 64) return;
    int n = t >> 6, k = t & 63;
    WT[t] = (k < KIN) ? f2b(in_W[k * HH + n]) : 0;
}

__global__ __launch_bounds__(256) void prep_x(const float* __restrict__ x,
                                              unsigned short* __restrict__ xb) {
    int t = blockIdx.x * 256 + threadIdx.x;
    if (t >= NN * 64) return;
    int n = t >> 6, c = t & 63;
    xb[t] = (c < KIN) ? f2b(x[n * KIN + c]) : 0;
}

// ============================ MFMA GEMM  C = A @ Bt^T ============================
// tile 128x128x64, 4 waves (2x2), each wave 64x64 via 4x4 16x16x32 frags.
// ZHM=0: C row-major [M][256]. ZHM=1: C head-major zT[c>>5][row][c&31]
// (per-head 3.2MB slices, L2-resident for the head-affine aggregate).
// Launch with gridDim.y = HH/128 = 2 ALWAYS.
template<int ZHM>
__global__ __launch_bounds__(256) void gemm_mfma(const unsigned short* __restrict__ A,
                                                 const unsigned short* __restrict__ Bt,
                                                 unsigned short* __restrict__ C,
                                                 int M, int K) {
    __shared__ unsigned short As[128 * 64];
    __shared__ unsigned short Bs[128 * 64];
    int row0 = blockIdx.x * 128;
    int n0 = blockIdx.y * 128;
    int tid = threadIdx.x;
    int w = tid >> 6, l = tid & 63;
    int wm = w >> 1, wn = w & 1;
    int r15 = l & 15, q = l >> 4;

    f32x4 acc[4][4] = {};

    int crow = l >> 3;     // row within 8-row chunk
    int cs   = l & 7;      // 16B slot within row

    for (int kt = 0; kt < K; kt += 64) {
        if (kt) __syncthreads();
#pragma unroll
        for (int c = 0; c < 4; ++c) {
            int r = w * 32 + c * 8 + crow;          // tile row 0..127
            int sg = cs ^ (r & 7);                  // pre-swizzled source slot
            int ga = row0 + r; if (ga >= M) ga = M - 1;
            gload16(&A[(size_t)ga * K + kt + sg * 8], &As[(w * 32 + c * 8) * 64]);
            int gb = n0 + r;                        // < 256 always
            gload16(&Bt[(size_t)gb * K + kt + sg * 8], &Bs[(w * 32 + c * 8) * 64]);
        }
        __syncthreads();
#pragma unroll
        for (int kk = 0; kk < 2; ++kk) {
            bf16x8 aF[4], bF[4];
#pragma unroll
            for (int i = 0; i < 4; ++i) {
                int ar = wm * 64 + i * 16 + r15;
                aF[i] = *(bf16x8*)&As[ar * 64 + ((kk * 4 + q) ^ (ar & 7)) * 8];
                int br = wn * 64 + i * 16 + r15;
                bF[i] = *(bf16x8*)&Bs[br * 64 + ((kk * 4 + q) ^ (br & 7)) * 8];
            }
#pragma unroll
            for (int i = 0; i < 4; ++i)
#pragma unroll
                for (int j = 0; j < 4; ++j)
                    acc[i][j] = __builtin_amdgcn_mfma_f32_16x16x32_bf16(aF[i], bF[j], acc[i][j], 0, 0, 0);
        }
    }

    // C/D layout: col = lane&15, row = (lane>>4)*4 + reg
#pragma unroll
    for (int i = 0; i < 4; ++i)
#pragma unroll
        for (int j = 0; j < 4; ++j) {
            int nc = n0 + wn * 64 + j * 16 + r15;
#pragma unroll
            for (int r = 0; r < 4; ++r) {
                int gr = row0 + wm * 64 + i * 16 + q * 4 + r;
                if (gr < M) {
                    if (ZHM)
                        C[(size_t)(nc >> 5) * NN * CC + (size_t)gr * CC + (nc & 31)] = f2b(acc[i][j][r]);
                    else
                        C[(size_t)gr * HH + nc] = f2b(acc[i][j][r]);
                }
            }
        }
}

// ============================ attention scores (zT head-major) ============================
__global__ __launch_bounds__(256) void attn_scores(const unsigned short* __restrict__ zT,
                                                   const float* __restrict__ asrc,
                                                   const float* __restrict__ adst,
                                                   float* __restrict__ esrcT,
                                                   float* __restrict__ edstT) {
    int t = blockIdx.x * 256 + threadIdx.x;
    if (t >= NN * NH) return;
    int hd = t / NN, n = t - hd * NN;
    const unsigned short* zp = zT + (size_t)hd * NN * CC + (size_t)n * CC;
    const float* ap = asrc + hd * CC;
    const float* bp = adst + hd * CC;
    float s = 0.f, d = 0.f;
#pragma unroll
    for (int c = 0; c < CC; c += 4) {
        ushort4 zv = *(const ushort4*)(zp + c);
        float z0 = b2f(zv.x), z1 = b2f(zv.y), z2 = b2f(zv.z), z3 = b2f(zv.w);
        s += z0 * ap[c] + z1 * ap[c + 1] + z2 * ap[c + 2] + z3 * ap[c + 3];
        d += z0 * bp[c] + z1 * bp[c + 1] + z2 * bp[c + 2] + z3 * bp[c + 3];
    }
    esrcT[t] = s;   // t == hd*NN + n
    edstT[t] = d;
}

// ============================ head-affine aggregate v5 (LDS-staged) ============================
// blockIdx.x & 7 == head -> round-robin dispatch pins head hd's z-slice (3.2MB)
// + esrcT slice (200KB) in ONE XCD's 4MB L2.
// Block = 32 nodes x 1 head. Phase A: 256 threads cooperatively stage the block's
// contiguous edge range (ssrc COALESCED) + resolve es=esrcT[hd][s] (scattered but
// 256-way parallel) into LDS. Phase B: each 8-lane group walks its node's staged
// list -- s/es from LDS (broadcast), ONE global load (8B z) per trip, 2-unrolled.
// Deterministic (sorted order, fixed unroll). No max-subtraction (|e| <~ 16).
#define MAXEB 2048   // max staged edges per 32-node block (rows <= 64 each)
__global__ __launch_bounds__(256) void aggregate(const int* __restrict__ rowptr,
                                                 const int* __restrict__ ssrc,
                                                 const float* __restrict__ esrcT,
                                                 const float* __restrict__ edstT,
                                                 const unsigned short* __restrict__ zT,
                                                 unsigned short* __restrict__ outb) {
    __shared__ int   s_lds[MAXEB];
    __shared__ float es_lds[MAXEB];
    __shared__ int   rp_lds[33];
    int bid = blockIdx.x;
    int hd = bid & 7;
    int n0 = (bid >> 3) * 32;
    int tid = threadIdx.x;
    const float* esp = esrcT + (size_t)hd * NN;
    const unsigned short* zp = zT + (size_t)hd * NN * CC;

    if (tid <= 32) {
        int idx = n0 + tid;
        rp_lds[tid] = rowptr[idx > NN ? NN : idx];
    }
    __syncthreads();
    int beg0 = rp_lds[0];
    int total = rp_lds[32] - beg0;
    bool staged = (total <= MAXEB);
    if (staged) {
        for (int j = tid; j < total; j += 256) {
            int s = ssrc[beg0 + j];
            s_lds[j] = s;
            es_lds[j] = esp[s];
        }
    }
    __syncthreads();

    int lane = tid & 63;
    int wv = tid >> 6;
    int g = lane >> 3;
    int nl = wv * 8 + g;                            // local node 0..31
    int n = n0 + nl;
    int col = (lane & 7) * 4;
    bool act = n < NN;
    float ed = act ? edstT[(size_t)hd * NN + n] : 0.f;
    int jbeg = rp_lds[nl] - beg0;
    int jend = rp_lds[nl + 1] - beg0;

    float den0 = 0.f, den1 = 0.f;
    float a0 = 0.f, a1 = 0.f, a2 = 0.f, a3 = 0.f;
    float b0 = 0.f, b1 = 0.f, b2 = 0.f, b3 = 0.f;
    int j = jbeg;
    if (staged) {
        for (; j + 1 < jend; j += 2) {
            int s0 = s_lds[j], s1 = s_lds[j + 1];
            float es0 = es_lds[j], es1 = es_lds[j + 1];
            ushort4 z0 = *(const ushort4*)&zp[(size_t)s0 * CC + col];
            ushort4 z1 = *(const ushort4*)&zp[(size_t)s1 * CC + col];
            float e0 = es0 + ed; e0 = (e0 > 0.f) ? e0 : 0.2f * e0;
            float e1 = es1 + ed; e1 = (e1 > 0.f) ? e1 : 0.2f * e1;
            float p0 = __expf(e0);
            float p1 = __expf(e1);
            den0 += p0;
            a0 += p0 * b2f(z0.x); a1 += p0 * b2f(z0.y);
            a2 += p0 * b2f(z0.z); a3 += p0 * b2f(z0.w);
            den1 += p1;
            b0 += p1 * b2f(z1.x); b1 += p1 * b2f(z1.y);
            b2 += p1 * b2f(z1.z); b3 += p1 * b2f(z1.w);
        }
        if (j < jend) {
            int s0 = s_lds[j];
            float es0 = es_lds[j];
            ushort4 z0 = *(const ushort4*)&zp[(size_t)s0 * CC + col];
            float e0 = es0 + ed; e0 = (e0 > 0.f) ? e0 : 0.2f * e0;
            float p0 = __expf(e0);
            den0 += p0;
            a0 += p0 * b2f(z0.x); a1 += p0 * b2f(z0.y);
            a2 += p0 * b2f(z0.z); a3 += p0 * b2f(z0.w);
        }
    } else {   // fallback (astronomically rare): identical math from global
        for (; j + 1 < jend; j += 2) {
            int s0 = ssrc[beg0 + j], s1 = ssrc[beg0 + j + 1];
            float es0 = esp[s0], es1 = esp[s1];
            ushort4 z0 = *(const ushort4*)&zp[(size_t)s0 * CC + col];
            ushort4 z1 = *(const ushort4*)&zp[(size_t)s1 * CC + col];
            float e0 = es0 + ed; e0 = (e0 > 0.f) ? e0 : 0.2f * e0;
            float e1 = es1 + ed; e1 = (e1 > 0.f) ? e1 : 0.2f * e1;
            float p0 = __expf(e0);
            float p1 = __expf(e1);
            den0 += p0;
            a0 += p0 * b2f(z0.x); a1 += p0 * b2f(z0.y);
            a2 += p0 * b2f(z0.z); a3 += p0 * b2f(z0.w);
            den1 += p1;
            b0 += p1 * b2f(z1.x); b1 += p1 * b2f(z1.y);
            b2 += p1 * b2f(z1.z); b3 += p1 * b2f(z1.w);
        }
        if (j < jend) {
            int s0 = ssrc[beg0 + j];
            float es0 = esp[s0];
            ushort4 z0 = *(const ushort4*)&zp[(size_t)s0 * CC + col];
            float e0 = es0 + ed; e0 = (e0 > 0.f) ? e0 : 0.2f * e0;
            float p0 = __expf(e0);
            den0 += p0;
            a0 += p0 * b2f(z0.x); a1 += p0 * b2f(z0.y);
            a2 += p0 * b2f(z0.z); a3 += p0 * b2f(z0.w);
        }
    }
    if (act) {
        float inv = 1.f / (den0 + den1);            // row nonempty (self loop)
        ushort4 o;
        o.x = f2b((a0 + b0) * inv); o.y = f2b((a1 + b1) * inv);
        o.z = f2b((a2 + b2) * inv); o.w = f2b((a3 + b3) * inv);
        *(ushort4*)&outb[(size_t)n * HH + hd * CC + col] = o;
    }
}

// ============================ BatchNorm ============================
__global__ __launch_bounds__(256) void col_stats(const unsigned short* __restrict__ X,
                                                 float* __restrict__ sums) {
    int c = threadIdx.x;
    int rows_per_block = (NN + gridDim.x - 1) / gridDim.x;
    int r0 = blockIdx.x * rows_per_block;
    int r1 = min(NN, r0 + rows_per_block);
    float s = 0.f, q = 0.f;
    for (int r = r0; r < r1; ++r) {
        float v = b2f(X[(size_t)r * HH + c]);
        s += v; q += v * v;
    }
    atomicAdd(&sums[c], s);
    atomicAdd(&sums[HH + c], q);
}

// out = relu((X-mean)*rstd*gamma+beta) [+ res]; all bf16; res/out may alias (same index).
__global__ __launch_bounds__(256) void bn_relu_add(const unsigned short* __restrict__ X,
                                                   const float* __restrict__ sums,
                                                   const float* __restrict__ gamma,
                                                   const float* __restrict__ beta,
                                                   const unsigned short* __restrict__ res,
                                                   unsigned short* __restrict__ outb) {
    int i = blockIdx.x * 256 + threadIdx.x;
    if (i >= NN * 64) return;
    int c4 = (i & 63) * 4;
    const float invN = 1.f / NN;
    ushort4 u = *(const ushort4*)(X + (size_t)i * 4);
    float v0 = b2f(u.x), v1 = b2f(u.y), v2 = b2f(u.z), v3 = b2f(u.w);
    float4 s1 = *(const float4*)&sums[c4];
    float4 s2 = *(const float4*)&sums[HH + c4];
    float4 gm = *(const float4*)&gamma[c4];
    float4 bt = *(const float4*)&beta[c4];
    float mn0 = s1.x * invN, mn1 = s1.y * invN, mn2 = s1.z * invN, mn3 = s1.w * invN;
    float rs0 = rsqrtf(fmaxf(s2.x * invN - mn0 * mn0, 0.f) + 1e-5f);
    float rs1 = rsqrtf(fmaxf(s2.y * invN - mn1 * mn1, 0.f) + 1e-5f);
    float rs2 = rsqrtf(fmaxf(s2.z * invN - mn2 * mn2, 0.f) + 1e-5f);
    float rs3 = rsqrtf(fmaxf(s2.w * invN - mn3 * mn3, 0.f) + 1e-5f);
    float r0 = fmaxf((v0 - mn0) * rs0 * gm.x + bt.x, 0.f);
    float r1 = fmaxf((v1 - mn1) * rs1 * gm.y + bt.y, 0.f);
    float r2 = fmaxf((v2 - mn2) * rs2 * gm.z + bt.z, 0.f);
    float r3 = fmaxf((v3 - mn3) * rs3 * gm.w + bt.w, 0.f);
    if (res) {
        ushort4 rv = *(const ushort4*)(res + (size_t)i * 4);
        r0 += b2f(rv.x); r1 += b2f(rv.y); r2 += b2f(rv.z); r3 += b2f(rv.w);
    }
    ushort4 ob;
    ob.x = f2b(r0); ob.y = f2b(r1); ob.z = f2b(r2); ob.w = f2b(r3);
    *(ushort4*)(outb + (size_t)i * 4) = ob;
}

// ============================ output projection (h bf16) ============================
__global__ __launch_bounds__(256) void out_proj(const unsigned short* __restrict__ h,
                                                const float* __restrict__ mW,
                                                const float* __restrict__ mb,
                                                const float* __restrict__ lW,
                                                const float* __restrict__ lb,
                                                float* __restrict__ out) {
    int wid = (blockIdx.x * 256 + threadIdx.x) >> 6;
    int lane = threadIdx.x & 63;
    if (wid >= NN) return;
    ushort4 hv = *(const ushort4*)&h[(size_t)wid * HH + lane * 4];
    float h0 = b2f(hv.x), h1 = b2f(hv.y), h2 = b2f(hv.z), h3 = b2f(hv.w);
    float4 wv = *(const float4*)&mW[lane * 4];
    float4 lv = *(const float4*)&lW[lane * 4];
    float sm = h0 * wv.x + h1 * wv.y + h2 * wv.z + h3 * wv.w;
    float sl = h0 * lv.x + h1 * lv.y + h2 * lv.z + h3 * lv.w;
    for (int off = 32; off > 0; off >>= 1) {
        sm += __shfl_down(sm, off);
        sl += __shfl_down(sl, off);
    }
    if (lane == 0) {
        out[wid] = sm + mb[0];
        float l = sl + lb[0];
        out[NN + wid] = fminf(10.f, fmaxf(-10.f, l));
    }
}

// ============================ launch ============================
extern "C" void kernel_launch(void* const* d_in, const int* in_sizes, int n_in,
                              void* d_out, int out_size, void* d_ws, size_t ws_size,
                              hipStream_t stream) {
    const float* x        = (const float*)d_in[0];
    const int*   ei       = (const int*)d_in[1];
    const float* in_W     = (const float*)d_in[2];
    const float* in_gamma = (const float*)d_in[4];
    const float* in_beta  = (const float*)d_in[5];
    const float* Ws       = (const float*)d_in[6];
    const float* att_src  = (const float*)d_in[7];
    const float* att_dst  = (const float*)d_in[8];
    const float* bn_gamma = (const float*)d_in[10];
    const float* bn_beta  = (const float*)d_in[11];
    const float* mean_W   = (const float*)d_in[12];
    const float* mean_b   = (const float*)d_in[13];
    const float* lv_W     = (const float*)d_in[14];
    const float* lv_b     = (const float*)d_in[15];
    float* out = (float*)d_out;

    // workspace layout (bytes)
    char* p = (char*)d_ws;
    unsigned short* z    = (unsigned short*)p; p += (size_t)NN * HH * 2;   // zT for layers
    unsigned short* hb   = (unsigned short*)p; p += (size_t)NN * HH * 2;
    unsigned short* aggb = (unsigned short*)p; p += (size_t)NN * HH * 2;
    float* esrcT = (float*)p;                  p += (size_t)NN * NH * 4;
    float* edstT = (float*)p;                  p += (size_t)NN * NH * 4;
    float* sums = (float*)p;                   p += 512 * 4;
    unsigned short* WT   = (unsigned short*)p; p += (size_t)LL * HH * HH * 2;
    unsigned short* inWT = (unsigned short*)p; p += (size_t)HH * 64 * 2;
    int* counts = (int*)p;                     p += (size_t)NN * 4;
    int* rowptr = (int*)p;                     p += (size_t)(NN + 1) * 4;
    int* cursor = (int*)p;                     p += (size_t)NN * 4;
    int* ssrc   = (int*)p;                     p += (size_t)ETOT * 4;
    int* bsums  = (int*)p;                     p += 64 * 4;
    unsigned short* xb = aggb;  // alias: xb dead before aggb first written

    // ---- CSR build (+ per-row source sort: locality + canonical order) ----
    hipMemsetAsync(counts, 0, NN * sizeof(int), stream);
    edge_hist<<<(ETOT + 255) / 256, 256, 0, stream>>>(ei, counts);
    scan1<<<SCAN_NBLK, 256, 0, stream>>>(counts, cursor, bsums);
    scan2<<<1, 64, 0, stream>>>(bsums);
    scan3<<<(NN + 255) / 256, 256, 0, stream>>>(cursor, bsums, counts, rowptr, cursor);
    edge_scatter<<<(ETOT + 255) / 256, 256, 0, stream>>>(ei, cursor, ssrc);
    sort_rows<<<(NN * 64 + 255) / 256, 256, 0, stream>>>(rowptr, ssrc);

    // ---- bf16 prep ----
    prep_wt<<<(LL * HH * HH + 255) / 256, 256, 0, stream>>>(Ws, WT);
    prep_inwt<<<(HH * 64 + 255) / 256, 256, 0, stream>>>(in_W, inWT);
    prep_x<<<(NN * 64 + 255) / 256, 256, 0, stream>>>(x, xb);

    // ---- input projection + BN + ReLU (row-major z: feeds only BN chain) ----
    {
        dim3 g((NN + 127) / 128, 2);
        gemm_mfma<0><<<g, 256, 0, stream>>>(xb, inWT, z, NN, 64);
    }
    hipMemsetAsync(sums, 0, 512 * sizeof(float), stream);
    col_stats<<<1024, 256, 0, stream>>>(z, sums);
    bn_relu_add<<<(NN * 64 + 255) / 256, 256, 0, stream>>>(z, sums, in_gamma, in_beta,
                                                           nullptr, hb);

    // ---- GAT layers ----
    for (int l = 0; l < LL; ++l) {
        const unsigned short* WTl = WT + (size_t)l * HH * HH;
        const float* asl = att_src + (size_t)l * NH * CC;
        const float* adl = att_dst + (size_t)l * NH * CC;
        const float* gl  = bn_gamma + (size_t)l * HH;
        const float* bl  = bn_beta + (size_t)l * HH;

        dim3 g((NN + 127) / 128, 2);
        gemm_mfma<1><<<g, 256, 0, stream>>>(hb, WTl, z, NN, HH);       // z head-major
        attn_scores<<<(NN * NH + 255) / 256, 256, 0, stream>>>(z, asl, adl, esrcT, edstT);
        aggregate<<<((NN + 31) / 32) * 8, 256, 0, stream>>>(rowptr, ssrc, esrcT, edstT, z, aggb);
        hipMemsetAsync(sums, 0, 512 * sizeof(float), stream);
        col_stats<<<1024, 256, 0, stream>>>(aggb, sums);
        bn_relu_add<<<(NN * 64 + 255) / 256, 256, 0, stream>>>(aggb, sums, gl, bl, hb, hb);
    }

    // ---- output heads ----
    out_proj<<<(NN * 64 + 255) / 256, 256, 0, stream>>>(hb, mean_W, mean_b, lv_W, lv_b, out);
}

// Round 11
// 826.440 us; speedup vs baseline: 1.4889x; 1.0040x over previous
//
#include <hip/hip_runtime.h>

#define NN 50000
#define EE 800000
#define ETOT 850000
#define KIN 61
#define HH 256
#define NH 8
#define CC 32
#define LL 4
#define SCAN_NBLK 49   // ceil(NN/1024)

typedef __attribute__((ext_vector_type(8))) short bf16x8;
typedef __attribute__((ext_vector_type(4))) float f32x4;

__device__ __forceinline__ unsigned short f2b(float f) {
    unsigned u = __builtin_bit_cast(unsigned, f);
    u += 0x7fffu + ((u >> 16) & 1u);   // RNE
    return (unsigned short)(u >> 16);
}
__device__ __forceinline__ float b2f(unsigned short h) {
    unsigned u = ((unsigned)h) << 16;
    return __builtin_bit_cast(float, u);
}

// async global->LDS, 16B per lane; LDS dest is wave-uniform base + lane*16
__device__ __forceinline__ void gload16(const void* g, void* l) {
    __builtin_amdgcn_global_load_lds(
        (const __attribute__((address_space(1))) void*)g,
        (__attribute__((address_space(3))) void*)l, 16, 0, 0);
}

// ============================ CSR build ============================

__global__ __launch_bounds__(256) void edge_hist(const int* __restrict__ ei,
                                                 int* __restrict__ counts) {
    int e = blockIdx.x * 256 + threadIdx.x;
    if (e >= ETOT) return;
    int d = (e < EE) ? ei[EE + e] : (e - EE);
    atomicAdd(&counts[d], 1);
}

__global__ __launch_bounds__(256) void scan1(const int* __restrict__ counts,
                                             int* __restrict__ tmp,
                                             int* __restrict__ bsums) {
    __shared__ int lds[256];
    int b = blockIdx.x, t = threadIdx.x;
    int base = b * 1024 + t * 4;
    int v0 = 0, v1 = 0, v2 = 0, v3 = 0;
    if (base + 0 < NN) v0 = counts[base + 0];
    if (base + 1 < NN) v1 = counts[base + 1];
    if (base + 2 < NN) v2 = counts[base + 2];
    if (base + 3 < NN) v3 = counts[base + 3];
    int s = v0 + v1 + v2 + v3;
    lds[t] = s;
    __syncthreads();
    for (int off = 1; off < 256; off <<= 1) {
        int x = (t >= off) ? lds[t - off] : 0;
        __syncthreads();
        lds[t] += x;
        __syncthreads();
    }
    int run = lds[t] - s;
    if (t == 255) bsums[b] = lds[255];
    run += v0; if (base + 0 < NN) tmp[base + 0] = run;
    run += v1; if (base + 1 < NN) tmp[base + 1] = run;
    run += v2; if (base + 2 < NN) tmp[base + 2] = run;
    run += v3; if (base + 3 < NN) tmp[base + 3] = run;
}

__global__ void scan2(int* __restrict__ bsums) {
    if (threadIdx.x == 0) {
        int acc = 0;
        for (int i = 0; i < SCAN_NBLK; ++i) { int t = bsums[i]; bsums[i] = acc; acc += t; }
    }
}

__global__ __launch_bounds__(256) void scan3(const int* __restrict__ tmp,
                                             const int* __restrict__ bsums,
                                             const int* __restrict__ counts,
                                             int* __restrict__ rowptr,
                                             int* __restrict__ cursor) {
    int i = blockIdx.x * 256 + threadIdx.x;
    if (i >= NN) return;
    int incl = tmp[i] + bsums[i >> 10];
    rowptr[i + 1] = incl;
    cursor[i] = incl - counts[i];
    if (i == 0) rowptr[0] = 0;
}

__global__ __launch_bounds__(256) void edge_scatter(const int* __restrict__ ei,
                                                    int* __restrict__ cursor,
                                                    int* __restrict__ ssrc) {
    int e = blockIdx.x * 256 + threadIdx.x;
    if (e >= ETOT) return;
    int s, d;
    if (e < EE) { s = ei[e]; d = ei[EE + e]; } else { s = d = e - EE; }
    int pos = atomicAdd(&cursor[d], 1);
    ssrc[pos] = s;
}

// sort each row's sources ascending (deterministic 64-lane bitonic).
__global__ __launch_bounds__(256) void sort_rows(const int* __restrict__ rowptr,
                                                 int* __restrict__ ssrc) {
    int wid = (blockIdx.x * 256 + threadIdx.x) >> 6;
    int lane = threadIdx.x & 63;
    if (wid >= NN) return;
    int beg = rowptr[wid], end = rowptr[wid + 1];
    int L = end - beg;
    if (L > 64) return;
    int v = (lane < L) ? ssrc[beg + lane] : 0x7fffffff;
#pragma unroll
    for (int k = 2; k <= 64; k <<= 1) {
#pragma unroll
        for (int j = k >> 1; j > 0; j >>= 1) {
            int partner = __shfl_xor(v, j);
            bool up = ((lane & k) == 0);
            bool keepMin = (up == ((lane & j) == 0));
            int mn = min(v, partner), mx = max(v, partner);
            v = keepMin ? mn : mx;
        }
    }
    if (lane < L) ssrc[beg + lane] = v;
}

// ============================ weight / input prep (bf16) ============================

__global__ __launch_bounds__(256) void prep_wt(const float* __restrict__ Ws,
                                               unsigned short* __restrict__ WT) {
    int t = blockIdx.x * 256 + threadIdx.x;
    if (t >= LL * HH * HH) return;
    int l = t >> 16, rem = t & 65535;
    int n = rem >> 8, k = rem & 255;
    WT[t] = f2b(Ws[l * 65536 + k * HH + n]);
}

__global__ __launch_bounds__(256) void prep_inwt(const float* __restrict__ in_W,
                                                 unsigned short* __restrict__ WT) {
    int t = blockIdx.x * 256 + threadIdx.x;
    if (t >= HH * 64) return;
    int n = t >> 6, k = t & 63;
    WT[t] = (k < KIN) ? f2b(in_W[k * HH + n]) : 0;
}

__global__ __launch_bounds__(256) void prep_x(const float* __restrict__ x,
                                              unsigned short* __restrict__ xb) {
    int t = blockIdx.x * 256 + threadIdx.x;
    if (t >= NN * 64) return;
    int n = t >> 6, c = t & 63;
    xb[t] = (c < KIN) ? f2b(x[n * KIN + c]) : 0;
}

// ============================ MFMA GEMM  C = A @ Bt^T ============================
// tile 128x128x64, 4 waves (2x2), each wave 64x64 via 4x4 16x16x32 frags.
// ZHM=0: C row-major [M][256]. ZHM=1: C head-major zT[c>>5][row][c&31]
// (per-head 3.2MB slices, L2-resident for the head-affine aggregate).
// Launch with gridDim.y = HH/128 = 2 ALWAYS.
template<int ZHM>
__global__ __launch_bounds__(256) void gemm_mfma(const unsigned short* __restrict__ A,
                                                 const unsigned short* __restrict__ Bt,
                                                 unsigned short* __restrict__ C,
                                                 int M, int K) {
    __shared__ unsigned short As[128 * 64];
    __shared__ unsigned short Bs[128 * 64];
    int row0 = blockIdx.x * 128;
    int n0 = blockIdx.y * 128;
    int tid = threadIdx.x;
    int w = tid >> 6, l = tid & 63;
    int wm = w >> 1, wn = w & 1;
    int r15 = l & 15, q = l >> 4;

    f32x4 acc[4][4] = {};

    int crow = l >> 3;     // row within 8-row chunk
    int cs   = l & 7;      // 16B slot within row

    for (int kt = 0; kt < K; kt += 64) {
        if (kt) __syncthreads();
#pragma unroll
        for (int c = 0; c < 4; ++c) {
            int r = w * 32 + c * 8 + crow;          // tile row 0..127
            int sg = cs ^ (r & 7);                  // pre-swizzled source slot
            int ga = row0 + r; if (ga >= M) ga = M - 1;
            gload16(&A[(size_t)ga * K + kt + sg * 8], &As[(w * 32 + c * 8) * 64]);
            int gb = n0 + r;                        // < 256 always
            gload16(&Bt[(size_t)gb * K + kt + sg * 8], &Bs[(w * 32 + c * 8) * 64]);
        }
        __syncthreads();
#pragma unroll
        for (int kk = 0; kk < 2; ++kk) {
            bf16x8 aF[4], bF[4];
#pragma unroll
            for (int i = 0; i < 4; ++i) {
                int ar = wm * 64 + i * 16 + r15;
                aF[i] = *(bf16x8*)&As[ar * 64 + ((kk * 4 + q) ^ (ar & 7)) * 8];
                int br = wn * 64 + i * 16 + r15;
                bF[i] = *(bf16x8*)&Bs[br * 64 + ((kk * 4 + q) ^ (br & 7)) * 8];
            }
#pragma unroll
            for (int i = 0; i < 4; ++i)
#pragma unroll
                for (int j = 0; j < 4; ++j)
                    acc[i][j] = __builtin_amdgcn_mfma_f32_16x16x32_bf16(aF[i], bF[j], acc[i][j], 0, 0, 0);
        }
    }

    // C/D layout: col = lane&15, row = (lane>>4)*4 + reg
#pragma unroll
    for (int i = 0; i < 4; ++i)
#pragma unroll
        for (int j = 0; j < 4; ++j) {
            int nc = n0 + wn * 64 + j * 16 + r15;
#pragma unroll
            for (int r = 0; r < 4; ++r) {
                int gr = row0 + wm * 64 + i * 16 + q * 4 + r;
                if (gr < M) {
                    if (ZHM)
                        C[(size_t)(nc >> 5) * NN * CC + (size_t)gr * CC + (nc & 31)] = f2b(acc[i][j][r]);
                    else
                        C[(size_t)gr * HH + nc] = f2b(acc[i][j][r]);
                }
            }
        }
}

// ============================ attention scores (zT head-major) ============================
__global__ __launch_bounds__(256) void attn_scores(const unsigned short* __restrict__ zT,
                                                   const float* __restrict__ asrc,
                                                   const float* __restrict__ adst,
                                                   float* __restrict__ esrcT,
                                                   float* __restrict__ edstT) {
    int t = blockIdx.x * 256 + threadIdx.x;
    if (t >= NN * NH) return;
    int hd = t / NN, n = t - hd * NN;
    const unsigned short* zp = zT + (size_t)hd * NN * CC + (size_t)n * CC;
    const float* ap = asrc + hd * CC;
    const float* bp = adst + hd * CC;
    float s = 0.f, d = 0.f;
#pragma unroll
    for (int c = 0; c < CC; c += 4) {
        ushort4 zv = *(const ushort4*)(zp + c);
        float z0 = b2f(zv.x), z1 = b2f(zv.y), z2 = b2f(zv.z), z3 = b2f(zv.w);
        s += z0 * ap[c] + z1 * ap[c + 1] + z2 * ap[c + 2] + z3 * ap[c + 3];
        d += z0 * bp[c] + z1 * bp[c + 1] + z2 * bp[c + 2] + z3 * bp[c + 3];
    }
    esrcT[t] = s;   // t == hd*NN + n
    edstT[t] = d;
}

// ============================ head-affine aggregate v6 (p precomputed in LDS) ============================
// blockIdx.x & 7 == head -> round-robin dispatch pins head hd's z-slice (3.2MB)
// + esrcT slice (200KB) in ONE XCD's 4MB L2.
// Block = 32 nodes x 1 head. Phase A: 256 threads stage the block's contiguous
// edge range; each thread finds its edge's OWNER node (5-step binary search over
// rp_lds) and computes p = exp(leaky(es+ed)) ONCE, storing (s, p) in LDS.
// Phase B: each 8-lane group walks its node's staged list -- s/p from LDS
// (broadcast), ONE global 8B z load + 5 FMA per edge. Exp count drops 8x.
// Bit-identical accumulation order vs v5. No max-subtraction (|e| <~ 16).
#define MAXEB 2048   // max staged edges per 32-node block (rows <= 64 each)
__global__ __launch_bounds__(256) void aggregate(const int* __restrict__ rowptr,
                                                 const int* __restrict__ ssrc,
                                                 const float* __restrict__ esrcT,
                                                 const float* __restrict__ edstT,
                                                 const unsigned short* __restrict__ zT,
                                                 unsigned short* __restrict__ outb) {
    __shared__ int   s_lds[MAXEB];
    __shared__ float p_lds[MAXEB];
    __shared__ int   rp_lds[33];
    __shared__ float ed_lds[32];
    int bid = blockIdx.x;
    int hd = bid & 7;
    int n0 = (bid >> 3) * 32;
    int tid = threadIdx.x;
    const float* esp = esrcT + (size_t)hd * NN;
    const unsigned short* zp = zT + (size_t)hd * NN * CC;

    if (tid <= 32) {
        int idx = n0 + tid;
        rp_lds[tid] = rowptr[idx > NN ? NN : idx];
    }
    if (tid < 32) {
        int nn = n0 + tid;
        ed_lds[tid] = (nn < NN) ? edstT[(size_t)hd * NN + nn] : 0.f;
    }
    __syncthreads();
    int beg0 = rp_lds[0];
    int total = rp_lds[32] - beg0;
    bool staged = (total <= MAXEB);
    if (staged) {
        for (int j = tid; j < total; j += 256) {
            int s = ssrc[beg0 + j];
            // owner: largest o in [0,32) with rp_lds[o] <= beg0+j (edges grouped by node)
            int jj = beg0 + j;
            int lo = 0, hi = 32;
#pragma unroll
            for (int st = 0; st < 5; ++st) {
                int mid = (lo + hi) >> 1;
                bool le = (rp_lds[mid] <= jj);
                lo = le ? mid : lo;
                hi = le ? hi : mid;
            }
            float e = esp[s] + ed_lds[lo];
            e = (e > 0.f) ? e : 0.2f * e;
            s_lds[j] = s;
            p_lds[j] = __expf(e);
        }
    }
    __syncthreads();

    int lane = tid & 63;
    int wv = tid >> 6;
    int g = lane >> 3;
    int nl = wv * 8 + g;                            // local node 0..31
    int n = n0 + nl;
    int col = (lane & 7) * 4;
    bool act = n < NN;
    int jbeg = rp_lds[nl] - beg0;
    int jend = rp_lds[nl + 1] - beg0;

    float den0 = 0.f, den1 = 0.f;
    float a0 = 0.f, a1 = 0.f, a2 = 0.f, a3 = 0.f;
    float b0 = 0.f, b1 = 0.f, b2 = 0.f, b3 = 0.f;
    int j = jbeg;
    if (staged) {
        for (; j + 1 < jend; j += 2) {
            int s0 = s_lds[j], s1 = s_lds[j + 1];
            float p0 = p_lds[j], p1 = p_lds[j + 1];
            ushort4 z0 = *(const ushort4*)&zp[(size_t)(s0 * CC + col)];
            ushort4 z1 = *(const ushort4*)&zp[(size_t)(s1 * CC + col)];
            den0 += p0;
            a0 += p0 * b2f(z0.x); a1 += p0 * b2f(z0.y);
            a2 += p0 * b2f(z0.z); a3 += p0 * b2f(z0.w);
            den1 += p1;
            b0 += p1 * b2f(z1.x); b1 += p1 * b2f(z1.y);
            b2 += p1 * b2f(z1.z); b3 += p1 * b2f(z1.w);
        }
        if (j < jend) {
            int s0 = s_lds[j];
            float p0 = p_lds[j];
            ushort4 z0 = *(const ushort4*)&zp[(size_t)(s0 * CC + col)];
            den0 += p0;
            a0 += p0 * b2f(z0.x); a1 += p0 * b2f(z0.y);
            a2 += p0 * b2f(z0.z); a3 += p0 * b2f(z0.w);
        }
    } else {   // fallback (astronomically rare): identical math from global
        float ed = act ? ed_lds[nl] : 0.f;
        for (; j + 1 < jend; j += 2) {
            int s0 = ssrc[beg0 + j], s1 = ssrc[beg0 + j + 1];
            float es0 = esp[s0], es1 = esp[s1];
            ushort4 z0 = *(const ushort4*)&zp[(size_t)(s0 * CC + col)];
            ushort4 z1 = *(const ushort4*)&zp[(size_t)(s1 * CC + col)];
            float e0 = es0 + ed; e0 = (e0 > 0.f) ? e0 : 0.2f * e0;
            float e1 = es1 + ed; e1 = (e1 > 0.f) ? e1 : 0.2f * e1;
            float p0 = __expf(e0);
            float p1 = __expf(e1);
            den0 += p0;
            a0 += p0 * b2f(z0.x); a1 += p0 * b2f(z0.y);
            a2 += p0 * b2f(z0.z); a3 += p0 * b2f(z0.w);
            den1 += p1;
            b0 += p1 * b2f(z1.x); b1 += p1 * b2f(z1.y);
            b2 += p1 * b2f(z1.z); b3 += p1 * b2f(z1.w);
        }
        if (j < jend) {
            int s0 = ssrc[beg0 + j];
            float es0 = esp[s0];
            ushort4 z0 = *(const ushort4*)&zp[(size_t)(s0 * CC + col)];
            float e0 = es0 + ed; e0 = (e0 > 0.f) ? e0 : 0.2f * e0;
            float p0 = __expf(e0);
            den0 += p0;
            a0 += p0 * b2f(z0.x); a1 += p0 * b2f(z0.y);
            a2 += p0 * b2f(z0.z); a3 += p0 * b2f(z0.w);
        }
    }
    if (act) {
        float inv = 1.f / (den0 + den1);            // row nonempty (self loop)
        ushort4 o;
        o.x = f2b((a0 + b0) * inv); o.y = f2b((a1 + b1) * inv);
        o.z = f2b((a2 + b2) * inv); o.w = f2b((a3 + b3) * inv);
        *(ushort4*)&outb[(size_t)n * HH + hd * CC + col] = o;
    }
}

// ============================ BatchNorm ============================
__global__ __launch_bounds__(256) void col_stats(const unsigned short* __restrict__ X,
                                                 float* __restrict__ sums) {
    int c = threadIdx.x;
    int rows_per_block = (NN + gridDim.x - 1) / gridDim.x;
    int r0 = blockIdx.x * rows_per_block;
    int r1 = min(NN, r0 + rows_per_block);
    float s = 0.f, q = 0.f;
    for (int r = r0; r < r1; ++r) {
        float v = b2f(X[(size_t)r * HH + c]);
        s += v; q += v * v;
    }
    atomicAdd(&sums[c], s);
    atomicAdd(&sums[HH + c], q);
}

// out = relu((X-mean)*rstd*gamma+beta) [+ res]; all bf16; res/out may alias (same index).
__global__ __launch_bounds__(256) void bn_relu_add(const unsigned short* __restrict__ X,
                                                   const float* __restrict__ sums,
                                                   const float* __restrict__ gamma,
                                                   const float* __restrict__ beta,
                                                   const unsigned short* __restrict__ res,
                                                   unsigned short* __restrict__ outb) {
    int i = blockIdx.x * 256 + threadIdx.x;
    if (i >= NN * 64) return;
    int c4 = (i & 63) * 4;
    const float invN = 1.f / NN;
    ushort4 u = *(const ushort4*)(X + (size_t)i * 4);
    float v0 = b2f(u.x), v1 = b2f(u.y), v2 = b2f(u.z), v3 = b2f(u.w);
    float4 s1 = *(const float4*)&sums[c4];
    float4 s2 = *(const float4*)&sums[HH + c4];
    float4 gm = *(const float4*)&gamma[c4];
    float4 bt = *(const float4*)&beta[c4];
    float mn0 = s1.x * invN, mn1 = s1.y * invN, mn2 = s1.z * invN, mn3 = s1.w * invN;
    float rs0 = rsqrtf(fmaxf(s2.x * invN - mn0 * mn0, 0.f) + 1e-5f);
    float rs1 = rsqrtf(fmaxf(s2.y * invN - mn1 * mn1, 0.f) + 1e-5f);
    float rs2 = rsqrtf(fmaxf(s2.z * invN - mn2 * mn2, 0.f) + 1e-5f);
    float rs3 = rsqrtf(fmaxf(s2.w * invN - mn3 * mn3, 0.f) + 1e-5f);
    float r0 = fmaxf((v0 - mn0) * rs0 * gm.x + bt.x, 0.f);
    float r1 = fmaxf((v1 - mn1) * rs1 * gm.y + bt.y, 0.f);
    float r2 = fmaxf((v2 - mn2) * rs2 * gm.z + bt.z, 0.f);
    float r3 = fmaxf((v3 - mn3) * rs3 * gm.w + bt.w, 0.f);
    if (res) {
        ushort4 rv = *(const ushort4*)(res + (size_t)i * 4);
        r0 += b2f(rv.x); r1 += b2f(rv.y); r2 += b2f(rv.z); r3 += b2f(rv.w);
    }
    ushort4 ob;
    ob.x = f2b(r0); ob.y = f2b(r1); ob.z = f2b(r2); ob.w = f2b(r3);
    *(ushort4*)(outb + (size_t)i * 4) = ob;
}

// ============================ output projection (h bf16) ============================
__global__ __launch_bounds__(256) void out_proj(const unsigned short* __restrict__ h,
                                                const float* __restrict__ mW,
                                                const float* __restrict__ mb,
                                                const float* __restrict__ lW,
                                                const float* __restrict__ lb,
                                                float* __restrict__ out) {
    int wid = (blockIdx.x * 256 + threadIdx.x) >> 6;
    int lane = threadIdx.x & 63;
    if (wid >= NN) return;
    ushort4 hv = *(const ushort4*)&h[(size_t)wid * HH + lane * 4];
    float h0 = b2f(hv.x), h1 = b2f(hv.y), h2 = b2f(hv.z), h3 = b2f(hv.w);
    float4 wv = *(const float4*)&mW[lane * 4];
    float4 lv = *(const float4*)&lW[lane * 4];
    float sm = h0 * wv.x + h1 * wv.y + h2 * wv.z + h3 * wv.w;
    float sl = h0 * lv.x + h1 * lv.y + h2 * lv.z + h3 * lv.w;
    for (int off = 32; off > 0; off >>= 1) {
        sm += __shfl_down(sm, off);
        sl += __shfl_down(sl, off);
    }
    if (lane == 0) {
        out[wid] = sm + mb[0];
        float l = sl + lb[0];
        out[NN + wid] = fminf(10.f, fmaxf(-10.f, l));
    }
}

// ============================ launch ============================
extern "C" void kernel_launch(void* const* d_in, const int* in_sizes, int n_in,
                              void* d_out, int out_size, void* d_ws, size_t ws_size,
                              hipStream_t stream) {
    const float* x        = (const float*)d_in[0];
    const int*   ei       = (const int*)d_in[1];
    const float* in_W     = (const float*)d_in[2];
    const float* in_gamma = (const float*)d_in[4];
    const float* in_beta  = (const float*)d_in[5];
    const float* Ws       = (const float*)d_in[6];
    const float* att_src  = (const float*)d_in[7];
    const float* att_dst  = (const float*)d_in[8];
    const float* bn_gamma = (const float*)d_in[10];
    const float* bn_beta  = (const float*)d_in[11];
    const float* mean_W   = (const float*)d_in[12];
    const float* mean_b   = (const float*)d_in[13];
    const float* lv_W     = (const float*)d_in[14];
    const float* lv_b     = (const float*)d_in[15];
    float* out = (float*)d_out;

    // workspace layout (bytes)
    char* p = (char*)d_ws;
    unsigned short* z    = (unsigned short*)p; p += (size_t)NN * HH * 2;   // zT for layers
    unsigned short* hb   = (unsigned short*)p; p += (size_t)NN * HH * 2;
    unsigned short* aggb = (unsigned short*)p; p += (size_t)NN * HH * 2;
    float* esrcT = (float*)p;                  p += (size_t)NN * NH * 4;
    float* edstT = (float*)p;                  p += (size_t)NN * NH * 4;
    float* sums = (float*)p;                   p += 512 * 4;
    unsigned short* WT   = (unsigned short*)p; p += (size_t)LL * HH * HH * 2;
    unsigned short* inWT = (unsigned short*)p; p += (size_t)HH * 64 * 2;
    int* counts = (int*)p;                     p += (size_t)NN * 4;
    int* rowptr = (int*)p;                     p += (size_t)(NN + 1) * 4;
    int* cursor = (int*)p;                     p += (size_t)NN * 4;
    int* ssrc   = (int*)p;                     p += (size_t)ETOT * 4;
    int* bsums  = (int*)p;                     p += 64 * 4;
    unsigned short* xb = aggb;  // alias: xb dead before aggb first written

    // ---- CSR build (+ per-row source sort: locality + canonical order) ----
    hipMemsetAsync(counts, 0, NN * sizeof(int), stream);
    edge_hist<<<(ETOT + 255) / 256, 256, 0, stream>>>(ei, counts);
    scan1<<<SCAN_NBLK, 256, 0, stream>>>(counts, cursor, bsums);
    scan2<<<1, 64, 0, stream>>>(bsums);
    scan3<<<(NN + 255) / 256, 256, 0, stream>>>(cursor, bsums, counts, rowptr, cursor);
    edge_scatter<<<(ETOT + 255) / 256, 256, 0, stream>>>(ei, cursor, ssrc);
    sort_rows<<<(NN * 64 + 255) / 256, 256, 0, stream>>>(rowptr, ssrc);

    // ---- bf16 prep ----
    prep_wt<<<(LL * HH * HH + 255) / 256, 256, 0, stream>>>(Ws, WT);
    prep_inwt<<<(HH * 64 + 255) / 256, 256, 0, stream>>>(in_W, inWT);
    prep_x<<<(NN * 64 + 255) / 256, 256, 0, stream>>>(x, xb);

    // ---- input projection + BN + ReLU (row-major z: feeds only BN chain) ----
    {
        dim3 g((NN + 127) / 128, 2);
        gemm_mfma<0><<<g, 256, 0, stream>>>(xb, inWT, z, NN, 64);
    }
    hipMemsetAsync(sums, 0, 512 * sizeof(float), stream);
    col_stats<<<1024, 256, 0, stream>>>(z, sums);
    bn_relu_add<<<(NN * 64 + 255) / 256, 256, 0, stream>>>(z, sums, in_gamma, in_beta,
                                                           nullptr, hb);

    // ---- GAT layers ----
    for (int l = 0; l < LL; ++l) {
        const unsigned short* WTl = WT + (size_t)l * HH * HH;
        const float* asl = att_src + (size_t)l * NH * CC;
        const float* adl = att_dst + (size_t)l * NH * CC;
        const float* gl  = bn_gamma + (size_t)l * HH;
        const float* bl  = bn_beta + (size_t)l * HH;

        dim3 g((NN + 127) / 128, 2);
        gemm_mfma<1><<<g, 256, 0, stream>>>(hb, WTl, z, NN, HH);       // z head-major
        attn_scores<<<(NN * NH + 255) / 256, 256, 0, stream>>>(z, asl, adl, esrcT, edstT);
        aggregate<<<((NN + 31) / 32) * 8, 256, 0, stream>>>(rowptr, ssrc, esrcT, edstT, z, aggb);
        hipMemsetAsync(sums, 0, 512 * sizeof(float), stream);
        col_stats<<<1024, 256, 0, stream>>>(aggb, sums);
        bn_relu_add<<<(NN * 64 + 255) / 256, 256, 0, stream>>>(aggb, sums, gl, bl, hb, hb);
    }

    // ---- output heads ----
    out_proj<<<(NN * 64 + 255) / 256, 256, 0, stream>>>(hb, mean_W, mean_b, lv_W, lv_b, out);
}

// Round 12
// 717.610 us; speedup vs baseline: 1.7147x; 1.1517x over previous
//
#include <hip/hip_runtime.h>

#define NN 50000
#define EE 800000
#define ETOT 850000
#define KIN 61
#define HH 256
#define NH 8
#define CC 32
#define LL 4
#define SCAN_NBLK 49   // ceil(NN/1024)

typedef __attribute__((ext_vector_type(8))) short bf16x8;
typedef __attribute__((ext_vector_type(4))) float f32x4;

__device__ __forceinline__ unsigned short f2b(float f) {
    unsigned u = __builtin_bit_cast(unsigned, f);
    u += 0x7fffu + ((u >> 16) & 1u);   // RNE
    return (unsigned short)(u >> 16);
}
__device__ __forceinline__ float b2f(unsigned short h) {
    unsigned u = ((unsigned)h) << 16;
    return __builtin_bit_cast(float, u);
}

// async global->LDS, 16B per lane; LDS dest is wave-uniform base + lane*16
__device__ __forceinline__ void gload16(const void* g, void* l) {
    __builtin_amdgcn_global_load_lds(
        (const __attribute__((address_space(1))) void*)g,
        (__attribute__((address_space(3))) void*)l, 16, 0, 0);
}

// ============================ CSR build ============================

__global__ __launch_bounds__(256) void edge_hist(const int* __restrict__ ei,
                                                 int* __restrict__ counts) {
    int e = blockIdx.x * 256 + threadIdx.x;
    if (e >= ETOT) return;
    int d = (e < EE) ? ei[EE + e] : (e - EE);
    atomicAdd(&counts[d], 1);
}

__global__ __launch_bounds__(256) void scan1(const int* __restrict__ counts,
                                             int* __restrict__ tmp,
                                             int* __restrict__ bsums) {
    __shared__ int lds[256];
    int b = blockIdx.x, t = threadIdx.x;
    int base = b * 1024 + t * 4;
    int v0 = 0, v1 = 0, v2 = 0, v3 = 0;
    if (base + 0 < NN) v0 = counts[base + 0];
    if (base + 1 < NN) v1 = counts[base + 1];
    if (base + 2 < NN) v2 = counts[base + 2];
    if (base + 3 < NN) v3 = counts[base + 3];
    int s = v0 + v1 + v2 + v3;
    lds[t] = s;
    __syncthreads();
    for (int off = 1; off < 256; off <<= 1) {
        int x = (t >= off) ? lds[t - off] : 0;
        __syncthreads();
        lds[t] += x;
        __syncthreads();
    }
    int run = lds[t] - s;
    if (t == 255) bsums[b] = lds[255];
    run += v0; if (base + 0 < NN) tmp[base + 0] = run;
    run += v1; if (base + 1 < NN) tmp[base + 1] = run;
    run += v2; if (base + 2 < NN) tmp[base + 2] = run;
    run += v3; if (base + 3 < NN) tmp[base + 3] = run;
}

__global__ void scan2(int* __restrict__ bsums) {
    if (threadIdx.x == 0) {
        int acc = 0;
        for (int i = 0; i < SCAN_NBLK; ++i) { int t = bsums[i]; bsums[i] = acc; acc += t; }
    }
}

__global__ __launch_bounds__(256) void scan3(const int* __restrict__ tmp,
                                             const int* __restrict__ bsums,
                                             const int* __restrict__ counts,
                                             int* __restrict__ rowptr,
                                             int* __restrict__ cursor) {
    int i = blockIdx.x * 256 + threadIdx.x;
    if (i >= NN) return;
    int incl = tmp[i] + bsums[i >> 10];
    rowptr[i + 1] = incl;
    cursor[i] = incl - counts[i];
    if (i == 0) rowptr[0] = 0;
}

__global__ __launch_bounds__(256) void edge_scatter(const int* __restrict__ ei,
                                                    int* __restrict__ cursor,
                                                    int* __restrict__ ssrc) {
    int e = blockIdx.x * 256 + threadIdx.x;
    if (e >= ETOT) return;
    int s, d;
    if (e < EE) { s = ei[e]; d = ei[EE + e]; } else { s = d = e - EE; }
    int pos = atomicAdd(&cursor[d], 1);
    ssrc[pos] = s;
}

// sort each row's sources ascending (deterministic 64-lane bitonic).
__global__ __launch_bounds__(256) void sort_rows(const int* __restrict__ rowptr,
                                                 int* __restrict__ ssrc) {
    int wid = (blockIdx.x * 256 + threadIdx.x) >> 6;
    int lane = threadIdx.x & 63;
    if (wid >= NN) return;
    int beg = rowptr[wid], end = rowptr[wid + 1];
    int L = end - beg;
    if (L > 64) return;
    int v = (lane < L) ? ssrc[beg + lane] : 0x7fffffff;
#pragma unroll
    for (int k = 2; k <= 64; k <<= 1) {
#pragma unroll
        for (int j = k >> 1; j > 0; j >>= 1) {
            int partner = __shfl_xor(v, j);
            bool up = ((lane & k) == 0);
            bool keepMin = (up == ((lane & j) == 0));
            int mn = min(v, partner), mx = max(v, partner);
            v = keepMin ? mn : mx;
        }
    }
    if (lane < L) ssrc[beg + lane] = v;
}

// ============================ weight / input prep (bf16) ============================

__global__ __launch_bounds__(256) void prep_wt(const float* __restrict__ Ws,
                                               unsigned short* __restrict__ WT) {
    int t = blockIdx.x * 256 + threadIdx.x;
    if (t >= LL * HH * HH) return;
    int l = t >> 16, rem = t & 65535;
    int n = rem >> 8, k = rem & 255;
    WT[t] = f2b(Ws[l * 65536 + k * HH + n]);
}

__global__ __launch_bounds__(256) void prep_inwt(const float* __restrict__ in_W,
                                                 unsigned short* __restrict__ WT) {
    int t = blockIdx.x * 256 + threadIdx.x;
    if (t >= HH * 64) return;
    int n = t >> 6, k = t & 63;
    WT[t] = (k < KIN) ? f2b(in_W[k * HH + n]) : 0;
}

__global__ __launch_bounds__(256) void prep_x(const float* __restrict__ x,
                                              unsigned short* __restrict__ xb) {
    int t = blockIdx.x * 256 + threadIdx.x;
    if (t >= NN * 64) return;
    int n = t >> 6, c = t & 63;
    xb[t] = (c < KIN) ? f2b(x[n * KIN + c]) : 0;
}

// ============================ MFMA GEMM  C = A @ Bt^T (+ fused attn scores) ============================
// tile 128x128x64, 4 waves (2x2), each wave 64x64 via 4x4 16x16x32 frags.
// ZHM=0: C row-major [M][256]. ZHM=1: C head-major zT[c>>5][row][c&31] AND fused
// attention scores: block covers 4 complete heads (128 cols), so es/ed are
// computed in-epilogue from the f2b-rounded acc (numerically identical to the
// old attn_scores kernel that read bf16 z) via 16-lane shfl_xor allreduce
// (offsets 1,2,4,8 stay within r15 bits -- never cross q row-groups).
// Launch with gridDim.y = HH/128 = 2 ALWAYS.
template<int ZHM>
__global__ __launch_bounds__(256) void gemm_mfma(const unsigned short* __restrict__ A,
                                                 const unsigned short* __restrict__ Bt,
                                                 unsigned short* __restrict__ C,
                                                 const float* __restrict__ asl,
                                                 const float* __restrict__ adl,
                                                 float* __restrict__ esrcT,
                                                 float* __restrict__ edstT,
                                                 int M, int K) {
    __shared__ unsigned short As[128 * 64];
    __shared__ unsigned short Bs[128 * 64];
    int row0 = blockIdx.x * 128;
    int n0 = blockIdx.y * 128;
    int tid = threadIdx.x;
    int w = tid >> 6, l = tid & 63;
    int wm = w >> 1, wn = w & 1;
    int r15 = l & 15, q = l >> 4;

    f32x4 acc[4][4] = {};

    int crow = l >> 3;     // row within 8-row chunk
    int cs   = l & 7;      // 16B slot within row

    for (int kt = 0; kt < K; kt += 64) {
        if (kt) __syncthreads();
#pragma unroll
        for (int c = 0; c < 4; ++c) {
            int r = w * 32 + c * 8 + crow;          // tile row 0..127
            int sg = cs ^ (r & 7);                  // pre-swizzled source slot
            int ga = row0 + r; if (ga >= M) ga = M - 1;
            gload16(&A[(size_t)ga * K + kt + sg * 8], &As[(w * 32 + c * 8) * 64]);
            int gb = n0 + r;                        // < 256 always
            gload16(&Bt[(size_t)gb * K + kt + sg * 8], &Bs[(w * 32 + c * 8) * 64]);
        }
        __syncthreads();
#pragma unroll
        for (int kk = 0; kk < 2; ++kk) {
            bf16x8 aF[4], bF[4];
#pragma unroll
            for (int i = 0; i < 4; ++i) {
                int ar = wm * 64 + i * 16 + r15;
                aF[i] = *(bf16x8*)&As[ar * 64 + ((kk * 4 + q) ^ (ar & 7)) * 8];
                int br = wn * 64 + i * 16 + r15;
                bF[i] = *(bf16x8*)&Bs[br * 64 + ((kk * 4 + q) ^ (br & 7)) * 8];
            }
#pragma unroll
            for (int i = 0; i < 4; ++i)
#pragma unroll
                for (int j = 0; j < 4; ++j)
                    acc[i][j] = __builtin_amdgcn_mfma_f32_16x16x32_bf16(aF[i], bF[j], acc[i][j], 0, 0, 0);
        }
    }

    // C/D layout: col = lane&15, row = (lane>>4)*4 + reg
#pragma unroll
    for (int i = 0; i < 4; ++i)
#pragma unroll
        for (int j = 0; j < 4; ++j) {
            int nc = n0 + wn * 64 + j * 16 + r15;
#pragma unroll
            for (int r = 0; r < 4; ++r) {
                int gr = row0 + wm * 64 + i * 16 + q * 4 + r;
                if (gr < M) {
                    if (ZHM)
                        C[(size_t)(nc >> 5) * NN * CC + (size_t)gr * CC + (nc & 31)] = f2b(acc[i][j][r]);
                    else
                        C[(size_t)gr * HH + nc] = f2b(acc[i][j][r]);
                }
            }
        }

    if constexpr (ZHM) {
        // fused attention scores. head of col: hd_local = wn*2 + (j>>1);
        // channel-in-head = (j&1)*16 + r15.
        int hdbase = (n0 >> 5) + wn * 2;
        float as_[4], ad_[4];
#pragma unroll
        for (int j = 0; j < 4; ++j) {
            int idx = (hdbase + (j >> 1)) * CC + (j & 1) * 16 + r15;
            as_[j] = asl[idx];
            ad_[j] = adl[idx];
        }
#pragma unroll
        for (int h = 0; h < 2; ++h) {
#pragma unroll
            for (int i = 0; i < 4; ++i) {
                float pes[4], ped[4];
#pragma unroll
                for (int r = 0; r < 4; ++r) {
                    float v0 = b2f(f2b(acc[i][2 * h][r]));
                    float v1 = b2f(f2b(acc[i][2 * h + 1][r]));
                    pes[r] = v0 * as_[2 * h] + v1 * as_[2 * h + 1];
                    ped[r] = v0 * ad_[2 * h] + v1 * ad_[2 * h + 1];
                }
#pragma unroll
                for (int off = 1; off <= 8; off <<= 1) {
#pragma unroll
                    for (int r = 0; r < 4; ++r) {
                        pes[r] += __shfl_xor(pes[r], off);
                        ped[r] += __shfl_xor(ped[r], off);
                    }
                }
                int hd = hdbase + h;
                if (r15 < 8) {
                    int r = r15 & 3;
                    int gr = row0 + wm * 64 + i * 16 + q * 4 + r;
                    if (gr < M) {
                        if (r15 < 4) esrcT[(size_t)hd * NN + gr] = pes[r];
                        else         edstT[(size_t)hd * NN + gr] = ped[r];
                    }
                }
            }
        }
    }
}

// ============================ head-affine aggregate v7 (v6 + fused col_stats) ============================
// blockIdx.x & 7 == head -> round-robin dispatch pins head hd's z-slice (3.2MB)
// + esrcT slice (200KB) in ONE XCD's 4MB L2.
// Block = 32 nodes x 1 head. Phase A: stage (s, p=exp(leaky(es+ed))) in LDS
// (owner node via 5-step binary search). Phase B: 8-lane group per node, one
// 8B z load + 5 FMA per edge. Epilogue: per-block column stats (butterfly over
// the 8 node-groups, fixed-order wave combine, 64 atomicAdds) -> col_stats
// dispatch deleted. Stats inputs are the f2b-rounded outputs (identical to the
// old col_stats which read bf16 aggb).
#define MAXEB 2048   // max staged edges per 32-node block (rows <= 64 each)
__global__ __launch_bounds__(256) void aggregate(const int* __restrict__ rowptr,
                                                 const int* __restrict__ ssrc,
                                                 const float* __restrict__ esrcT,
                                                 const float* __restrict__ edstT,
                                                 const unsigned short* __restrict__ zT,
                                                 unsigned short* __restrict__ outb,
                                                 float* __restrict__ sums) {
    __shared__ int   s_lds[MAXEB];
    __shared__ float p_lds[MAXEB];
    __shared__ int   rp_lds[33];
    __shared__ float ed_lds[32];
    __shared__ float ws1[4][8][4], ws2[4][8][4];
    int bid = blockIdx.x;
    int hd = bid & 7;
    int n0 = (bid >> 3) * 32;
    int tid = threadIdx.x;
    const float* esp = esrcT + (size_t)hd * NN;
    const unsigned short* zp = zT + (size_t)hd * NN * CC;

    if (tid <= 32) {
        int idx = n0 + tid;
        rp_lds[tid] = rowptr[idx > NN ? NN : idx];
    }
    if (tid < 32) {
        int nn = n0 + tid;
        ed_lds[tid] = (nn < NN) ? edstT[(size_t)hd * NN + nn] : 0.f;
    }
    __syncthreads();
    int beg0 = rp_lds[0];
    int total = rp_lds[32] - beg0;
    bool staged = (total <= MAXEB);
    if (staged) {
        for (int j = tid; j < total; j += 256) {
            int s = ssrc[beg0 + j];
            int jj = beg0 + j;
            int lo = 0, hi = 32;
#pragma unroll
            for (int st = 0; st < 5; ++st) {
                int mid = (lo + hi) >> 1;
                bool le = (rp_lds[mid] <= jj);
                lo = le ? mid : lo;
                hi = le ? hi : mid;
            }
            float e = esp[s] + ed_lds[lo];
            e = (e > 0.f) ? e : 0.2f * e;
            s_lds[j] = s;
            p_lds[j] = __expf(e);
        }
    }
    __syncthreads();

    int lane = tid & 63;
    int wv = tid >> 6;
    int g = lane >> 3;
    int nl = wv * 8 + g;                            // local node 0..31
    int n = n0 + nl;
    int col = (lane & 7) * 4;
    bool act = n < NN;
    int jbeg = rp_lds[nl] - beg0;
    int jend = rp_lds[nl + 1] - beg0;

    float den0 = 0.f, den1 = 0.f;
    float a0 = 0.f, a1 = 0.f, a2 = 0.f, a3 = 0.f;
    float b0 = 0.f, b1 = 0.f, b2 = 0.f, b3 = 0.f;
    int j = jbeg;
    if (staged) {
        for (; j + 1 < jend; j += 2) {
            int s0 = s_lds[j], s1 = s_lds[j + 1];
            float p0 = p_lds[j], p1 = p_lds[j + 1];
            ushort4 z0 = *(const ushort4*)&zp[(size_t)(s0 * CC + col)];
            ushort4 z1 = *(const ushort4*)&zp[(size_t)(s1 * CC + col)];
            den0 += p0;
            a0 += p0 * b2f(z0.x); a1 += p0 * b2f(z0.y);
            a2 += p0 * b2f(z0.z); a3 += p0 * b2f(z0.w);
            den1 += p1;
            b0 += p1 * b2f(z1.x); b1 += p1 * b2f(z1.y);
            b2 += p1 * b2f(z1.z); b3 += p1 * b2f(z1.w);
        }
        if (j < jend) {
            int s0 = s_lds[j];
            float p0 = p_lds[j];
            ushort4 z0 = *(const ushort4*)&zp[(size_t)(s0 * CC + col)];
            den0 += p0;
            a0 += p0 * b2f(z0.x); a1 += p0 * b2f(z0.y);
            a2 += p0 * b2f(z0.z); a3 += p0 * b2f(z0.w);
        }
    } else {   // fallback (astronomically rare): identical math from global
        float ed = act ? ed_lds[nl] : 0.f;
        for (; j + 1 < jend; j += 2) {
            int s0 = ssrc[beg0 + j], s1 = ssrc[beg0 + j + 1];
            float es0 = esp[s0], es1 = esp[s1];
            ushort4 z0 = *(const ushort4*)&zp[(size_t)(s0 * CC + col)];
            ushort4 z1 = *(const ushort4*)&zp[(size_t)(s1 * CC + col)];
            float e0 = es0 + ed; e0 = (e0 > 0.f) ? e0 : 0.2f * e0;
            float e1 = es1 + ed; e1 = (e1 > 0.f) ? e1 : 0.2f * e1;
            float p0 = __expf(e0);
            float p1 = __expf(e1);
            den0 += p0;
            a0 += p0 * b2f(z0.x); a1 += p0 * b2f(z0.y);
            a2 += p0 * b2f(z0.z); a3 += p0 * b2f(z0.w);
            den1 += p1;
            b0 += p1 * b2f(z1.x); b1 += p1 * b2f(z1.y);
            b2 += p1 * b2f(z1.z); b3 += p1 * b2f(z1.w);
        }
        if (j < jend) {
            int s0 = ssrc[beg0 + j];
            float es0 = esp[s0];
            ushort4 z0 = *(const ushort4*)&zp[(size_t)(s0 * CC + col)];
            float e0 = es0 + ed; e0 = (e0 > 0.f) ? e0 : 0.2f * e0;
            float p0 = __expf(e0);
            den0 += p0;
            a0 += p0 * b2f(z0.x); a1 += p0 * b2f(z0.y);
            a2 += p0 * b2f(z0.z); a3 += p0 * b2f(z0.w);
        }
    }
    float v0 = 0.f, v1 = 0.f, v2 = 0.f, v3 = 0.f;
    if (act) {
        float inv = 1.f / (den0 + den1);            // row nonempty (self loop)
        ushort4 o;
        o.x = f2b((a0 + b0) * inv); o.y = f2b((a1 + b1) * inv);
        o.z = f2b((a2 + b2) * inv); o.w = f2b((a3 + b3) * inv);
        *(ushort4*)&outb[(size_t)n * HH + hd * CC + col] = o;
        v0 = b2f(o.x); v1 = b2f(o.y); v2 = b2f(o.z); v3 = b2f(o.w);
    }
    // fused column stats over this block's 32 nodes (rounded values, like col_stats)
    float q0 = v0 * v0, q1 = v1 * v1, q2 = v2 * v2, q3 = v3 * v3;
#pragma unroll
    for (int off = 8; off <= 32; off <<= 1) {
        v0 += __shfl_xor(v0, off); v1 += __shfl_xor(v1, off);
        v2 += __shfl_xor(v2, off); v3 += __shfl_xor(v3, off);
        q0 += __shfl_xor(q0, off); q1 += __shfl_xor(q1, off);
        q2 += __shfl_xor(q2, off); q3 += __shfl_xor(q3, off);
    }
    if (g == 0) {
        int slot = lane & 7;
        ws1[wv][slot][0] = v0; ws1[wv][slot][1] = v1;
        ws1[wv][slot][2] = v2; ws1[wv][slot][3] = v3;
        ws2[wv][slot][0] = q0; ws2[wv][slot][1] = q1;
        ws2[wv][slot][2] = q2; ws2[wv][slot][3] = q3;
    }
    __syncthreads();
    if (tid < 32) {
        int slot = tid & 7, k = tid >> 3;
        float s1v = ws1[0][slot][k] + ws1[1][slot][k] + ws1[2][slot][k] + ws1[3][slot][k];
        float s2v = ws2[0][slot][k] + ws2[1][slot][k] + ws2[2][slot][k] + ws2[3][slot][k];
        int ch = hd * CC + slot * 4 + k;
        atomicAdd(&sums[ch], s1v);
        atomicAdd(&sums[HH + ch], s2v);
    }
}

// ============================ BatchNorm (input projection only) ============================
__global__ __launch_bounds__(256) void col_stats(const unsigned short* __restrict__ X,
                                                 float* __restrict__ sums) {
    int c = threadIdx.x;
    int rows_per_block = (NN + gridDim.x - 1) / gridDim.x;
    int r0 = blockIdx.x * rows_per_block;
    int r1 = min(NN, r0 + rows_per_block);
    float s = 0.f, q = 0.f;
    for (int r = r0; r < r1; ++r) {
        float v = b2f(X[(size_t)r * HH + c]);
        s += v; q += v * v;
    }
    atomicAdd(&sums[c], s);
    atomicAdd(&sums[HH + c], q);
}

// out = relu((X-mean)*rstd*gamma+beta) [+ res]; all bf16; res/out may alias (same index).
__global__ __launch_bounds__(256) void bn_relu_add(const unsigned short* __restrict__ X,
                                                   const float* __restrict__ sums,
                                                   const float* __restrict__ gamma,
                                                   const float* __restrict__ beta,
                                                   const unsigned short* __restrict__ res,
                                                   unsigned short* __restrict__ outb) {
    int i = blockIdx.x * 256 + threadIdx.x;
    if (i >= NN * 64) return;
    int c4 = (i & 63) * 4;
    const float invN = 1.f / NN;
    ushort4 u = *(const ushort4*)(X + (size_t)i * 4);
    float v0 = b2f(u.x), v1 = b2f(u.y), v2 = b2f(u.z), v3 = b2f(u.w);
    float4 s1 = *(const float4*)&sums[c4];
    float4 s2 = *(const float4*)&sums[HH + c4];
    float4 gm = *(const float4*)&gamma[c4];
    float4 bt = *(const float4*)&beta[c4];
    float mn0 = s1.x * invN, mn1 = s1.y * invN, mn2 = s1.z * invN, mn3 = s1.w * invN;
    float rs0 = rsqrtf(fmaxf(s2.x * invN - mn0 * mn0, 0.f) + 1e-5f);
    float rs1 = rsqrtf(fmaxf(s2.y * invN - mn1 * mn1, 0.f) + 1e-5f);
    float rs2 = rsqrtf(fmaxf(s2.z * invN - mn2 * mn2, 0.f) + 1e-5f);
    float rs3 = rsqrtf(fmaxf(s2.w * invN - mn3 * mn3, 0.f) + 1e-5f);
    float r0 = fmaxf((v0 - mn0) * rs0 * gm.x + bt.x, 0.f);
    float r1 = fmaxf((v1 - mn1) * rs1 * gm.y + bt.y, 0.f);
    float r2 = fmaxf((v2 - mn2) * rs2 * gm.z + bt.z, 0.f);
    float r3 = fmaxf((v3 - mn3) * rs3 * gm.w + bt.w, 0.f);
    if (res) {
        ushort4 rv = *(const ushort4*)(res + (size_t)i * 4);
        r0 += b2f(rv.x); r1 += b2f(rv.y); r2 += b2f(rv.z); r3 += b2f(rv.w);
    }
    ushort4 ob;
    ob.x = f2b(r0); ob.y = f2b(r1); ob.z = f2b(r2); ob.w = f2b(r3);
    *(ushort4*)(outb + (size_t)i * 4) = ob;
}

// ============================ output projection (h bf16) ============================
__global__ __launch_bounds__(256) void out_proj(const unsigned short* __restrict__ h,
                                                const float* __restrict__ mW,
                                                const float* __restrict__ mb,
                                                const float* __restrict__ lW,
                                                const float* __restrict__ lb,
                                                float* __restrict__ out) {
    int wid = (blockIdx.x * 256 + threadIdx.x) >> 6;
    int lane = threadIdx.x & 63;
    if (wid >= NN) return;
    ushort4 hv = *(const ushort4*)&h[(size_t)wid * HH + lane * 4];
    float h0 = b2f(hv.x), h1 = b2f(hv.y), h2 = b2f(hv.z), h3 = b2f(hv.w);
    float4 wv = *(const float4*)&mW[lane * 4];
    float4 lv = *(const float4*)&lW[lane * 4];
    float sm = h0 * wv.x + h1 * wv.y + h2 * wv.z + h3 * wv.w;
    float sl = h0 * lv.x + h1 * lv.y + h2 * lv.z + h3 * lv.w;
    for (int off = 32; off > 0; off >>= 1) {
        sm += __shfl_down(sm, off);
        sl += __shfl_down(sl, off);
    }
    if (lane == 0) {
        out[wid] = sm + mb[0];
        float l = sl + lb[0];
        out[NN + wid] = fminf(10.f, fmaxf(-10.f, l));
    }
}

// ============================ launch ============================
extern "C" void kernel_launch(void* const* d_in, const int* in_sizes, int n_in,
                              void* d_out, int out_size, void* d_ws, size_t ws_size,
                              hipStream_t stream) {
    const float* x        = (const float*)d_in[0];
    const int*   ei       = (const int*)d_in[1];
    const float* in_W     = (const float*)d_in[2];
    const float* in_gamma = (const float*)d_in[4];
    const float* in_beta  = (const float*)d_in[5];
    const float* Ws       = (const float*)d_in[6];
    const float* att_src  = (const float*)d_in[7];
    const float* att_dst  = (const float*)d_in[8];
    const float* bn_gamma = (const float*)d_in[10];
    const float* bn_beta  = (const float*)d_in[11];
    const float* mean_W   = (const float*)d_in[12];
    const float* mean_b   = (const float*)d_in[13];
    const float* lv_W     = (const float*)d_in[14];
    const float* lv_b     = (const float*)d_in[15];
    float* out = (float*)d_out;

    // workspace layout (bytes)
    char* p = (char*)d_ws;
    unsigned short* z    = (unsigned short*)p; p += (size_t)NN * HH * 2;   // zT for layers
    unsigned short* hb   = (unsigned short*)p; p += (size_t)NN * HH * 2;
    unsigned short* aggb = (unsigned short*)p; p += (size_t)NN * HH * 2;
    float* esrcT = (float*)p;                  p += (size_t)NN * NH * 4;
    float* edstT = (float*)p;                  p += (size_t)NN * NH * 4;
    float* sums = (float*)p;                   p += 512 * 4;
    unsigned short* WT   = (unsigned short*)p; p += (size_t)LL * HH * HH * 2;
    unsigned short* inWT = (unsigned short*)p; p += (size_t)HH * 64 * 2;
    int* counts = (int*)p;                     p += (size_t)NN * 4;
    int* rowptr = (int*)p;                     p += (size_t)(NN + 1) * 4;
    int* cursor = (int*)p;                     p += (size_t)NN * 4;
    int* ssrc   = (int*)p;                     p += (size_t)ETOT * 4;
    int* bsums  = (int*)p;                     p += 64 * 4;
    unsigned short* xb = aggb;  // alias: xb dead before aggb first written

    // ---- CSR build (+ per-row source sort: locality + canonical order) ----
    hipMemsetAsync(counts, 0, NN * sizeof(int), stream);
    edge_hist<<<(ETOT + 255) / 256, 256, 0, stream>>>(ei, counts);
    scan1<<<SCAN_NBLK, 256, 0, stream>>>(counts, cursor, bsums);
    scan2<<<1, 64, 0, stream>>>(bsums);
    scan3<<<(NN + 255) / 256, 256, 0, stream>>>(cursor, bsums, counts, rowptr, cursor);
    edge_scatter<<<(ETOT + 255) / 256, 256, 0, stream>>>(ei, cursor, ssrc);
    sort_rows<<<(NN * 64 + 255) / 256, 256, 0, stream>>>(rowptr, ssrc);

    // ---- bf16 prep ----
    prep_wt<<<(LL * HH * HH + 255) / 256, 256, 0, stream>>>(Ws, WT);
    prep_inwt<<<(HH * 64 + 255) / 256, 256, 0, stream>>>(in_W, inWT);
    prep_x<<<(NN * 64 + 255) / 256, 256, 0, stream>>>(x, xb);

    // ---- input projection + BN + ReLU (row-major z: feeds only BN chain) ----
    {
        dim3 g((NN + 127) / 128, 2);
        gemm_mfma<0><<<g, 256, 0, stream>>>(xb, inWT, z, nullptr, nullptr,
                                            nullptr, nullptr, NN, 64);
    }
    hipMemsetAsync(sums, 0, 512 * sizeof(float), stream);
    col_stats<<<1024, 256, 0, stream>>>(z, sums);
    bn_relu_add<<<(NN * 64 + 255) / 256, 256, 0, stream>>>(z, sums, in_gamma, in_beta,
                                                           nullptr, hb);

    // ---- GAT layers ----
    for (int l = 0; l < LL; ++l) {
        const unsigned short* WTl = WT + (size_t)l * HH * HH;
        const float* asl = att_src + (size_t)l * NH * CC;
        const float* adl = att_dst + (size_t)l * NH * CC;
        const float* gl  = bn_gamma + (size_t)l * HH;
        const float* bl  = bn_beta + (size_t)l * HH;

        dim3 g((NN + 127) / 128, 2);
        // GEMM writes head-major z AND es/ed (attn_scores fused into epilogue)
        gemm_mfma<1><<<g, 256, 0, stream>>>(hb, WTl, z, asl, adl, esrcT, edstT, NN, HH);
        hipMemsetAsync(sums, 0, 512 * sizeof(float), stream);
        // aggregate also accumulates column stats (col_stats fused)
        aggregate<<<((NN + 31) / 32) * 8, 256, 0, stream>>>(rowptr, ssrc, esrcT, edstT,
                                                            z, aggb, sums);
        bn_relu_add<<<(NN * 64 + 255) / 256, 256, 0, stream>>>(aggb, sums, gl, bl, hb, hb);
    }

    // ---- output heads ----
    out_proj<<<(NN * 64 + 255) / 256, 256, 0, stream>>>(hb, mean_W, mean_b, lv_W, lv_b, out);
}

// Round 13
// 689.161 us; speedup vs baseline: 1.7854x; 1.0413x over previous
//
#include <hip/hip_runtime.h>

#define NN 50000
#define EE 800000
#define ETOT 850000
#define KIN 61
#define HH 256
#define NH 8
#define CC 32
#define LL 4
#define SCAN_NBLK 49   // ceil(NN/1024)

typedef __attribute__((ext_vector_type(8))) short bf16x8;
typedef __attribute__((ext_vector_type(4))) float f32x4;

__device__ __forceinline__ unsigned short f2b(float f) {
    unsigned u = __builtin_bit_cast(unsigned, f);
    u += 0x7fffu + ((u >> 16) & 1u);   // RNE
    return (unsigned short)(u >> 16);
}
__device__ __forceinline__ float b2f(unsigned short h) {
    unsigned u = ((unsigned)h) << 16;
    return __builtin_bit_cast(float, u);
}

// async global->LDS, 16B per lane; LDS dest is wave-uniform base + lane*16
__device__ __forceinline__ void gload16(const void* g, void* l) {
    __builtin_amdgcn_global_load_lds(
        (const __attribute__((address_space(1))) void*)g,
        (__attribute__((address_space(3))) void*)l, 16, 0, 0);
}

// ============================ CSR build ============================

__global__ __launch_bounds__(256) void edge_hist(const int* __restrict__ ei,
                                                 int* __restrict__ counts) {
    int e = blockIdx.x * 256 + threadIdx.x;
    if (e >= ETOT) return;
    int d = (e < EE) ? ei[EE + e] : (e - EE);
    atomicAdd(&counts[d], 1);
}

__global__ __launch_bounds__(256) void scan1(const int* __restrict__ counts,
                                             int* __restrict__ tmp,
                                             int* __restrict__ bsums) {
    __shared__ int lds[256];
    int b = blockIdx.x, t = threadIdx.x;
    int base = b * 1024 + t * 4;
    int v0 = 0, v1 = 0, v2 = 0, v3 = 0;
    if (base + 0 < NN) v0 = counts[base + 0];
    if (base + 1 < NN) v1 = counts[base + 1];
    if (base + 2 < NN) v2 = counts[base + 2];
    if (base + 3 < NN) v3 = counts[base + 3];
    int s = v0 + v1 + v2 + v3;
    lds[t] = s;
    __syncthreads();
    for (int off = 1; off < 256; off <<= 1) {
        int x = (t >= off) ? lds[t - off] : 0;
        __syncthreads();
        lds[t] += x;
        __syncthreads();
    }
    int run = lds[t] - s;
    if (t == 255) bsums[b] = lds[255];
    run += v0; if (base + 0 < NN) tmp[base + 0] = run;
    run += v1; if (base + 1 < NN) tmp[base + 1] = run;
    run += v2; if (base + 2 < NN) tmp[base + 2] = run;
    run += v3; if (base + 3 < NN) tmp[base + 3] = run;
}

__global__ void scan2(int* __restrict__ bsums) {
    if (threadIdx.x == 0) {
        int acc = 0;
        for (int i = 0; i < SCAN_NBLK; ++i) { int t = bsums[i]; bsums[i] = acc; acc += t; }
    }
}

__global__ __launch_bounds__(256) void scan3(const int* __restrict__ tmp,
                                             const int* __restrict__ bsums,
                                             const int* __restrict__ counts,
                                             int* __restrict__ rowptr,
                                             int* __restrict__ cursor) {
    int i = blockIdx.x * 256 + threadIdx.x;
    if (i >= NN) return;
    int incl = tmp[i] + bsums[i >> 10];
    rowptr[i + 1] = incl;
    cursor[i] = incl - counts[i];
    if (i == 0) rowptr[0] = 0;
}

__global__ __launch_bounds__(256) void edge_scatter(const int* __restrict__ ei,
                                                    int* __restrict__ cursor,
                                                    int* __restrict__ ssrc) {
    int e = blockIdx.x * 256 + threadIdx.x;
    if (e >= ETOT) return;
    int s, d;
    if (e < EE) { s = ei[e]; d = ei[EE + e]; } else { s = d = e - EE; }
    int pos = atomicAdd(&cursor[d], 1);
    ssrc[pos] = s;
}

// sort each row's sources ascending (deterministic 64-lane bitonic).
__global__ __launch_bounds__(256) void sort_rows(const int* __restrict__ rowptr,
                                                 int* __restrict__ ssrc) {
    int wid = (blockIdx.x * 256 + threadIdx.x) >> 6;
    int lane = threadIdx.x & 63;
    if (wid >= NN) return;
    int beg = rowptr[wid], end = rowptr[wid + 1];
    int L = end - beg;
    if (L > 64) return;
    int v = (lane < L) ? ssrc[beg + lane] : 0x7fffffff;
#pragma unroll
    for (int k = 2; k <= 64; k <<= 1) {
#pragma unroll
        for (int j = k >> 1; j > 0; j >>= 1) {
            int partner = __shfl_xor(v, j);
            bool up = ((lane & k) == 0);
            bool keepMin = (up == ((lane & j) == 0));
            int mn = min(v, partner), mx = max(v, partner);
            v = keepMin ? mn : mx;
        }
    }
    if (lane < L) ssrc[beg + lane] = v;
}

// ============================ weight / input prep (bf16) ============================

__global__ __launch_bounds__(256) void prep_wt(const float* __restrict__ Ws,
                                               unsigned short* __restrict__ WT) {
    int t = blockIdx.x * 256 + threadIdx.x;
    if (t >= LL * HH * HH) return;
    int l = t >> 16, rem = t & 65535;
    int n = rem >> 8, k = rem & 255;
    WT[t] = f2b(Ws[l * 65536 + k * HH + n]);
}

__global__ __launch_bounds__(256) void prep_inwt(const float* __restrict__ in_W,
                                                 unsigned short* __restrict__ WT) {
    int t = blockIdx.x * 256 + threadIdx.x;
    if (t >= HH * 64) return;
    int n = t >> 6, k = t & 63;
    WT[t] = (k < KIN) ? f2b(in_W[k * HH + n]) : 0;
}

__global__ __launch_bounds__(256) void prep_x(const float* __restrict__ x,
                                              unsigned short* __restrict__ xb) {
    int t = blockIdx.x * 256 + threadIdx.x;
    if (t >= NN * 64) return;
    int n = t >> 6, c = t & 63;
    xb[t] = (c < KIN) ? f2b(x[n * KIN + c]) : 0;
}

// ============================ MFMA GEMM  C = A @ Bt^T (+ fused attn scores) ============================
// tile 128 rows x 256 cols x 64 K, 8 waves (512 thr) arranged 2(wm) x 4(wn);
// each wave 64x64 via 4x4 16x16x32 frags. A staged ONCE (full 256-col output
// per block -> no gridDim.y); Bs holds all 256 B-rows. LDS 48KB -> 3 blk/CU.
// ZHM=0: C row-major [M][256]. ZHM=1: C head-major zT[c>>5][row][c&31] + fused
// attention scores (each wave covers 2 complete heads; 16-lane shfl_xor
// allreduce, offsets 1..8 stay within q-groups). Grid: (ceil(M/128), 1).
template<int ZHM>
__global__ __launch_bounds__(512) void gemm_mfma(const unsigned short* __restrict__ A,
                                                 const unsigned short* __restrict__ Bt,
                                                 unsigned short* __restrict__ C,
                                                 const float* __restrict__ asl,
                                                 const float* __restrict__ adl,
                                                 float* __restrict__ esrcT,
                                                 float* __restrict__ edstT,
                                                 int M, int K) {
    __shared__ unsigned short As[128 * 64];   // 16 KB
    __shared__ unsigned short Bs[256 * 64];   // 32 KB
    int row0 = blockIdx.x * 128;
    int tid = threadIdx.x;
    int w = tid >> 6, l = tid & 63;
    int wm = w >> 2, wn = w & 3;
    int r15 = l & 15, q = l >> 4;

    f32x4 acc[4][4] = {};

    int crow = l >> 3;     // row within 8-row chunk
    int cs   = l & 7;      // 16B slot within row

    for (int kt = 0; kt < K; kt += 64) {
        if (kt) __syncthreads();
        // stage A: wave w stages rows w*16 .. w*16+15 (2 chunks of 8)
#pragma unroll
        for (int c = 0; c < 2; ++c) {
            int r = w * 16 + c * 8 + crow;          // 0..127
            int sg = cs ^ (r & 7);
            int ga = row0 + r; if (ga >= M) ga = M - 1;
            gload16(&A[(size_t)ga * K + kt + sg * 8], &As[(w * 16 + c * 8) * 64]);
        }
        // stage B: wave w stages rows w*32 .. w*32+31 (4 chunks of 8)
#pragma unroll
        for (int c = 0; c < 4; ++c) {
            int r = w * 32 + c * 8 + crow;          // 0..255
            int sg = cs ^ (r & 7);
            gload16(&Bt[(size_t)r * K + kt + sg * 8], &Bs[(w * 32 + c * 8) * 64]);
        }
        __syncthreads();
#pragma unroll
        for (int kk = 0; kk < 2; ++kk) {
            bf16x8 aF[4], bF[4];
#pragma unroll
            for (int i = 0; i < 4; ++i) {
                int ar = wm * 64 + i * 16 + r15;
                aF[i] = *(bf16x8*)&As[ar * 64 + ((kk * 4 + q) ^ (ar & 7)) * 8];
                int br = wn * 64 + i * 16 + r15;
                bF[i] = *(bf16x8*)&Bs[br * 64 + ((kk * 4 + q) ^ (br & 7)) * 8];
            }
#pragma unroll
            for (int i = 0; i < 4; ++i)
#pragma unroll
                for (int j = 0; j < 4; ++j)
                    acc[i][j] = __builtin_amdgcn_mfma_f32_16x16x32_bf16(aF[i], bF[j], acc[i][j], 0, 0, 0);
        }
    }

    // C/D layout: col = lane&15, row = (lane>>4)*4 + reg
#pragma unroll
    for (int i = 0; i < 4; ++i)
#pragma unroll
        for (int j = 0; j < 4; ++j) {
            int nc = wn * 64 + j * 16 + r15;
#pragma unroll
            for (int r = 0; r < 4; ++r) {
                int gr = row0 + wm * 64 + i * 16 + q * 4 + r;
                if (gr < M) {
                    if (ZHM)
                        C[(size_t)(nc >> 5) * NN * CC + (size_t)gr * CC + (nc & 31)] = f2b(acc[i][j][r]);
                    else
                        C[(size_t)gr * HH + nc] = f2b(acc[i][j][r]);
                }
            }
        }

    if constexpr (ZHM) {
        // fused attention scores. head of col j: hd = wn*2 + (j>>1);
        // channel-in-head = (j&1)*16 + r15.  (verified epilogue, r12)
        int hdbase = wn * 2;
        float as_[4], ad_[4];
#pragma unroll
        for (int j = 0; j < 4; ++j) {
            int idx = (hdbase + (j >> 1)) * CC + (j & 1) * 16 + r15;
            as_[j] = asl[idx];
            ad_[j] = adl[idx];
        }
#pragma unroll
        for (int h = 0; h < 2; ++h) {
#pragma unroll
            for (int i = 0; i < 4; ++i) {
                float pes[4], ped[4];
#pragma unroll
                for (int r = 0; r < 4; ++r) {
                    float v0 = b2f(f2b(acc[i][2 * h][r]));
                    float v1 = b2f(f2b(acc[i][2 * h + 1][r]));
                    pes[r] = v0 * as_[2 * h] + v1 * as_[2 * h + 1];
                    ped[r] = v0 * ad_[2 * h] + v1 * ad_[2 * h + 1];
                }
#pragma unroll
                for (int off = 1; off <= 8; off <<= 1) {
#pragma unroll
                    for (int r = 0; r < 4; ++r) {
                        pes[r] += __shfl_xor(pes[r], off);
                        ped[r] += __shfl_xor(ped[r], off);
                    }
                }
                int hd = hdbase + h;
                if (r15 < 8) {
                    int r = r15 & 3;
                    int gr = row0 + wm * 64 + i * 16 + q * 4 + r;
                    if (gr < M) {
                        if (r15 < 4) esrcT[(size_t)hd * NN + gr] = pes[r];
                        else         edstT[(size_t)hd * NN + gr] = ped[r];
                    }
                }
            }
        }
    }
}

// ============================ head-affine aggregate v8 (4-unrolled phase B) ============================
// blockIdx.x & 7 == head -> round-robin dispatch pins head hd's z-slice (3.2MB)
// + esrcT slice (200KB) in ONE XCD's 4MB L2.
// Block = 32 nodes x 1 head. Phase A: stage (s, p=exp(leaky(es+ed))) in LDS
// (owner node via 5-step binary search). Phase B: 8-lane group per node, one
// 8B z load + 5 FMA per edge, 4 independent accumulator banks for ILP.
// Epilogue: fused per-block column stats -> col_stats dispatch deleted.
#define MAXEB 2048   // max staged edges per 32-node block (rows <= 64 each)
__global__ __launch_bounds__(256) void aggregate(const int* __restrict__ rowptr,
                                                 const int* __restrict__ ssrc,
                                                 const float* __restrict__ esrcT,
                                                 const float* __restrict__ edstT,
                                                 const unsigned short* __restrict__ zT,
                                                 unsigned short* __restrict__ outb,
                                                 float* __restrict__ sums) {
    __shared__ int   s_lds[MAXEB];
    __shared__ float p_lds[MAXEB];
    __shared__ int   rp_lds[33];
    __shared__ float ed_lds[32];
    __shared__ float ws1[4][8][4], ws2[4][8][4];
    int bid = blockIdx.x;
    int hd = bid & 7;
    int n0 = (bid >> 3) * 32;
    int tid = threadIdx.x;
    const float* esp = esrcT + (size_t)hd * NN;
    const unsigned short* zp = zT + (size_t)hd * NN * CC;

    if (tid <= 32) {
        int idx = n0 + tid;
        rp_lds[tid] = rowptr[idx > NN ? NN : idx];
    }
    if (tid < 32) {
        int nn = n0 + tid;
        ed_lds[tid] = (nn < NN) ? edstT[(size_t)hd * NN + nn] : 0.f;
    }
    __syncthreads();
    int beg0 = rp_lds[0];
    int total = rp_lds[32] - beg0;
    bool staged = (total <= MAXEB);
    if (staged) {
        for (int j = tid; j < total; j += 256) {
            int s = ssrc[beg0 + j];
            int jj = beg0 + j;
            int lo = 0, hi = 32;
#pragma unroll
            for (int st = 0; st < 5; ++st) {
                int mid = (lo + hi) >> 1;
                bool le = (rp_lds[mid] <= jj);
                lo = le ? mid : lo;
                hi = le ? hi : mid;
            }
            float e = esp[s] + ed_lds[lo];
            e = (e > 0.f) ? e : 0.2f * e;
            s_lds[j] = s;
            p_lds[j] = __expf(e);
        }
    }
    __syncthreads();

    int lane = tid & 63;
    int wv = tid >> 6;
    int g = lane >> 3;
    int nl = wv * 8 + g;                            // local node 0..31
    int n = n0 + nl;
    int col = (lane & 7) * 4;
    bool act = n < NN;
    int jbeg = rp_lds[nl] - beg0;
    int jend = rp_lds[nl + 1] - beg0;

    float d0 = 0.f, d1 = 0.f, d2 = 0.f, d3 = 0.f;
    float a00 = 0.f, a01 = 0.f, a02 = 0.f, a03 = 0.f;
    float a10 = 0.f, a11 = 0.f, a12 = 0.f, a13 = 0.f;
    float a20 = 0.f, a21 = 0.f, a22 = 0.f, a23 = 0.f;
    float a30 = 0.f, a31 = 0.f, a32 = 0.f, a33 = 0.f;
    int j = jbeg;
    if (staged) {
        for (; j + 3 < jend; j += 4) {
            int s0 = s_lds[j], s1 = s_lds[j + 1], s2 = s_lds[j + 2], s3 = s_lds[j + 3];
            float p0 = p_lds[j], p1 = p_lds[j + 1], p2 = p_lds[j + 2], p3 = p_lds[j + 3];
            ushort4 z0 = *(const ushort4*)&zp[(size_t)(s0 * CC + col)];
            ushort4 z1 = *(const ushort4*)&zp[(size_t)(s1 * CC + col)];
            ushort4 z2 = *(const ushort4*)&zp[(size_t)(s2 * CC + col)];
            ushort4 z3 = *(const ushort4*)&zp[(size_t)(s3 * CC + col)];
            d0 += p0;
            a00 += p0 * b2f(z0.x); a01 += p0 * b2f(z0.y);
            a02 += p0 * b2f(z0.z); a03 += p0 * b2f(z0.w);
            d1 += p1;
            a10 += p1 * b2f(z1.x); a11 += p1 * b2f(z1.y);
            a12 += p1 * b2f(z1.z); a13 += p1 * b2f(z1.w);
            d2 += p2;
            a20 += p2 * b2f(z2.x); a21 += p2 * b2f(z2.y);
            a22 += p2 * b2f(z2.z); a23 += p2 * b2f(z2.w);
            d3 += p3;
            a30 += p3 * b2f(z3.x); a31 += p3 * b2f(z3.y);
            a32 += p3 * b2f(z3.z); a33 += p3 * b2f(z3.w);
        }
        for (; j < jend; ++j) {
            int s0 = s_lds[j];
            float p0 = p_lds[j];
            ushort4 z0 = *(const ushort4*)&zp[(size_t)(s0 * CC + col)];
            d0 += p0;
            a00 += p0 * b2f(z0.x); a01 += p0 * b2f(z0.y);
            a02 += p0 * b2f(z0.z); a03 += p0 * b2f(z0.w);
        }
    } else {   // fallback (astronomically rare): identical math from global
        float ed = act ? ed_lds[nl] : 0.f;
        for (; j < jend; ++j) {
            int s0 = ssrc[beg0 + j];
            float es0 = esp[s0];
            ushort4 z0 = *(const ushort4*)&zp[(size_t)(s0 * CC + col)];
            float e0 = es0 + ed; e0 = (e0 > 0.f) ? e0 : 0.2f * e0;
            float p0 = __expf(e0);
            d0 += p0;
            a00 += p0 * b2f(z0.x); a01 += p0 * b2f(z0.y);
            a02 += p0 * b2f(z0.z); a03 += p0 * b2f(z0.w);
        }
    }
    float v0 = 0.f, v1 = 0.f, v2 = 0.f, v3 = 0.f;
    if (act) {
        float den = (d0 + d1) + (d2 + d3);          // row nonempty (self loop)
        float inv = 1.f / den;
        ushort4 o;
        o.x = f2b(((a00 + a10) + (a20 + a30)) * inv);
        o.y = f2b(((a01 + a11) + (a21 + a31)) * inv);
        o.z = f2b(((a02 + a12) + (a22 + a32)) * inv);
        o.w = f2b(((a03 + a13) + (a23 + a33)) * inv);
        *(ushort4*)&outb[(size_t)n * HH + hd * CC + col] = o;
        v0 = b2f(o.x); v1 = b2f(o.y); v2 = b2f(o.z); v3 = b2f(o.w);
    }
    // fused column stats over this block's 32 nodes (rounded values, like col_stats)
    float q0 = v0 * v0, q1 = v1 * v1, q2 = v2 * v2, q3 = v3 * v3;
#pragma unroll
    for (int off = 8; off <= 32; off <<= 1) {
        v0 += __shfl_xor(v0, off); v1 += __shfl_xor(v1, off);
        v2 += __shfl_xor(v2, off); v3 += __shfl_xor(v3, off);
        q0 += __shfl_xor(q0, off); q1 += __shfl_xor(q1, off);
        q2 += __shfl_xor(q2, off); q3 += __shfl_xor(q3, off);
    }
    if (g == 0) {
        int slot = lane & 7;
        ws1[wv][slot][0] = v0; ws1[wv][slot][1] = v1;
        ws1[wv][slot][2] = v2; ws1[wv][slot][3] = v3;
        ws2[wv][slot][0] = q0; ws2[wv][slot][1] = q1;
        ws2[wv][slot][2] = q2; ws2[wv][slot][3] = q3;
    }
    __syncthreads();
    if (tid < 32) {
        int slot = tid & 7, k = tid >> 3;
        float s1v = ws1[0][slot][k] + ws1[1][slot][k] + ws1[2][slot][k] + ws1[3][slot][k];
        float s2v = ws2[0][slot][k] + ws2[1][slot][k] + ws2[2][slot][k] + ws2[3][slot][k];
        int ch = hd * CC + slot * 4 + k;
        atomicAdd(&sums[ch], s1v);
        atomicAdd(&sums[HH + ch], s2v);
    }
}

// ============================ BatchNorm (input projection only) ============================
__global__ __launch_bounds__(256) void col_stats(const unsigned short* __restrict__ X,
                                                 float* __restrict__ sums) {
    int c = threadIdx.x;
    int rows_per_block = (NN + gridDim.x - 1) / gridDim.x;
    int r0 = blockIdx.x * rows_per_block;
    int r1 = min(NN, r0 + rows_per_block);
    float s = 0.f, q = 0.f;
    for (int r = r0; r < r1; ++r) {
        float v = b2f(X[(size_t)r * HH + c]);
        s += v; q += v * v;
    }
    atomicAdd(&sums[c], s);
    atomicAdd(&sums[HH + c], q);
}

// out = relu((X-mean)*rstd*gamma+beta) [+ res]; all bf16; res/out may alias (same index).
__global__ __launch_bounds__(256) void bn_relu_add(const unsigned short* __restrict__ X,
                                                   const float* __restrict__ sums,
                                                   const float* __restrict__ gamma,
                                                   const float* __restrict__ beta,
                                                   const unsigned short* __restrict__ res,
                                                   unsigned short* __restrict__ outb) {
    int i = blockIdx.x * 256 + threadIdx.x;
    if (i >= NN * 64) return;
    int c4 = (i & 63) * 4;
    const float invN = 1.f / NN;
    ushort4 u = *(const ushort4*)(X + (size_t)i * 4);
    float v0 = b2f(u.x), v1 = b2f(u.y), v2 = b2f(u.z), v3 = b2f(u.w);
    float4 s1 = *(const float4*)&sums[c4];
    float4 s2 = *(const float4*)&sums[HH + c4];
    float4 gm = *(const float4*)&gamma[c4];
    float4 bt = *(const float4*)&beta[c4];
    float mn0 = s1.x * invN, mn1 = s1.y * invN, mn2 = s1.z * invN, mn3 = s1.w * invN;
    float rs0 = rsqrtf(fmaxf(s2.x * invN - mn0 * mn0, 0.f) + 1e-5f);
    float rs1 = rsqrtf(fmaxf(s2.y * invN - mn1 * mn1, 0.f) + 1e-5f);
    float rs2 = rsqrtf(fmaxf(s2.z * invN - mn2 * mn2, 0.f) + 1e-5f);
    float rs3 = rsqrtf(fmaxf(s2.w * invN - mn3 * mn3, 0.f) + 1e-5f);
    float r0 = fmaxf((v0 - mn0) * rs0 * gm.x + bt.x, 0.f);
    float r1 = fmaxf((v1 - mn1) * rs1 * gm.y + bt.y, 0.f);
    float r2 = fmaxf((v2 - mn2) * rs2 * gm.z + bt.z, 0.f);
    float r3 = fmaxf((v3 - mn3) * rs3 * gm.w + bt.w, 0.f);
    if (res) {
        ushort4 rv = *(const ushort4*)(res + (size_t)i * 4);
        r0 += b2f(rv.x); r1 += b2f(rv.y); r2 += b2f(rv.z); r3 += b2f(rv.w);
    }
    ushort4 ob;
    ob.x = f2b(r0); ob.y = f2b(r1); ob.z = f2b(r2); ob.w = f2b(r3);
    *(ushort4*)(outb + (size_t)i * 4) = ob;
}

// ============================ output projection (h bf16) ============================
__global__ __launch_bounds__(256) void out_proj(const unsigned short* __restrict__ h,
                                                const float* __restrict__ mW,
                                                const float* __restrict__ mb,
                                                const float* __restrict__ lW,
                                                const float* __restrict__ lb,
                                                float* __restrict__ out) {
    int wid = (blockIdx.x * 256 + threadIdx.x) >> 6;
    int lane = threadIdx.x & 63;
    if (wid >= NN) return;
    ushort4 hv = *(const ushort4*)&h[(size_t)wid * HH + lane * 4];
    float h0 = b2f(hv.x), h1 = b2f(hv.y), h2 = b2f(hv.z), h3 = b2f(hv.w);
    float4 wv = *(const float4*)&mW[lane * 4];
    float4 lv = *(const float4*)&lW[lane * 4];
    float sm = h0 * wv.x + h1 * wv.y + h2 * wv.z + h3 * wv.w;
    float sl = h0 * lv.x + h1 * lv.y + h2 * lv.z + h3 * lv.w;
    for (int off = 32; off > 0; off >>= 1) {
        sm += __shfl_down(sm, off);
        sl += __shfl_down(sl, off);
    }
    if (lane == 0) {
        out[wid] = sm + mb[0];
        float l = sl + lb[0];
        out[NN + wid] = fminf(10.f, fmaxf(-10.f, l));
    }
}

// ============================ launch ============================
extern "C" void kernel_launch(void* const* d_in, const int* in_sizes, int n_in,
                              void* d_out, int out_size, void* d_ws, size_t ws_size,
                              hipStream_t stream) {
    const float* x        = (const float*)d_in[0];
    const int*   ei       = (const int*)d_in[1];
    const float* in_W     = (const float*)d_in[2];
    const float* in_gamma = (const float*)d_in[4];
    const float* in_beta  = (const float*)d_in[5];
    const float* Ws       = (const float*)d_in[6];
    const float* att_src  = (const float*)d_in[7];
    const float* att_dst  = (const float*)d_in[8];
    const float* bn_gamma = (const float*)d_in[10];
    const float* bn_beta  = (const float*)d_in[11];
    const float* mean_W   = (const float*)d_in[12];
    const float* mean_b   = (const float*)d_in[13];
    const float* lv_W     = (const float*)d_in[14];
    const float* lv_b     = (const float*)d_in[15];
    float* out = (float*)d_out;

    // workspace layout (bytes)
    char* p = (char*)d_ws;
    unsigned short* z    = (unsigned short*)p; p += (size_t)NN * HH * 2;   // zT for layers
    unsigned short* hb   = (unsigned short*)p; p += (size_t)NN * HH * 2;
    unsigned short* aggb = (unsigned short*)p; p += (size_t)NN * HH * 2;
    float* esrcT = (float*)p;                  p += (size_t)NN * NH * 4;
    float* edstT = (float*)p;                  p += (size_t)NN * NH * 4;
    float* sums = (float*)p;                   p += 512 * 4;
    unsigned short* WT   = (unsigned short*)p; p += (size_t)LL * HH * HH * 2;
    unsigned short* inWT = (unsigned short*)p; p += (size_t)HH * 64 * 2;
    int* counts = (int*)p;                     p += (size_t)NN * 4;
    int* rowptr = (int*)p;                     p += (size_t)(NN + 1) * 4;
    int* cursor = (int*)p;                     p += (size_t)NN * 4;
    int* ssrc   = (int*)p;                     p += (size_t)ETOT * 4;
    int* bsums  = (int*)p;                     p += 64 * 4;
    unsigned short* xb = aggb;  // alias: xb dead before aggb first written

    // ---- CSR build (+ per-row source sort: locality + canonical order) ----
    hipMemsetAsync(counts, 0, NN * sizeof(int), stream);
    edge_hist<<<(ETOT + 255) / 256, 256, 0, stream>>>(ei, counts);
    scan1<<<SCAN_NBLK, 256, 0, stream>>>(counts, cursor, bsums);
    scan2<<<1, 64, 0, stream>>>(bsums);
    scan3<<<(NN + 255) / 256, 256, 0, stream>>>(cursor, bsums, counts, rowptr, cursor);
    edge_scatter<<<(ETOT + 255) / 256, 256, 0, stream>>>(ei, cursor, ssrc);
    sort_rows<<<(NN * 64 + 255) / 256, 256, 0, stream>>>(rowptr, ssrc);

    // ---- bf16 prep ----
    prep_wt<<<(LL * HH * HH + 255) / 256, 256, 0, stream>>>(Ws, WT);
    prep_inwt<<<(HH * 64 + 255) / 256, 256, 0, stream>>>(in_W, inWT);
    prep_x<<<(NN * 64 + 255) / 256, 256, 0, stream>>>(x, xb);

    // ---- input projection + BN + ReLU (row-major z: feeds only BN chain) ----
    gemm_mfma<0><<<(NN + 127) / 128, 512, 0, stream>>>(xb, inWT, z, nullptr, nullptr,
                                                       nullptr, nullptr, NN, 64);
    hipMemsetAsync(sums, 0, 512 * sizeof(float), stream);
    col_stats<<<1024, 256, 0, stream>>>(z, sums);
    bn_relu_add<<<(NN * 64 + 255) / 256, 256, 0, stream>>>(z, sums, in_gamma, in_beta,
                                                           nullptr, hb);

    // ---- GAT layers ----
    for (int l = 0; l < LL; ++l) {
        const unsigned short* WTl = WT + (size_t)l * HH * HH;
        const float* asl = att_src + (size_t)l * NH * CC;
        const float* adl = att_dst + (size_t)l * NH * CC;
        const float* gl  = bn_gamma + (size_t)l * HH;
        const float* bl  = bn_beta + (size_t)l * HH;

        // GEMM writes head-major z AND es/ed (attn_scores fused into epilogue)
        gemm_mfma<1><<<(NN + 127) / 128, 512, 0, stream>>>(hb, WTl, z, asl, adl,
                                                           esrcT, edstT, NN, HH);
        hipMemsetAsync(sums, 0, 512 * sizeof(float), stream);
        // aggregate also accumulates column stats (col_stats fused)
        aggregate<<<((NN + 31) / 32) * 8, 256, 0, stream>>>(rowptr, ssrc, esrcT, edstT,
                                                            z, aggb, sums);
        bn_relu_add<<<(NN * 64 + 255) / 256, 256, 0, stream>>>(aggb, sums, gl, bl, hb, hb);
    }

    // ---- output heads ----
    out_proj<<<(NN * 64 + 255) / 256, 256, 0, stream>>>(hb, mean_W, mean_b, lv_W, lv_b, out);
}